// Round 1
// baseline (4642.634 us; speedup 1.0000x reference)
//
#include <hip/hip_runtime.h>
#include <hip/hip_bf16.h>

constexpr float LN_EPS = 1e-5f;

// ---------------------------------------------------------------------------
// Scatter-add: one thread per (edge, float4 chunk). D = feature dim (128/256).
// Also counts in-degree (once per edge) when cnt != nullptr.
// ---------------------------------------------------------------------------
template<int D>
__global__ __launch_bounds__(256)
void scatter_add_kernel(const float* __restrict__ feat, const int* __restrict__ src,
                        const int* __restrict__ dst, float* __restrict__ agg,
                        float* __restrict__ cnt, int E)
{
    constexpr int TPE = D / 4;
    long long gid = (long long)blockIdx.x * 256 + threadIdx.x;
    if (gid >= (long long)E * TPE) return;
    int e = (int)(gid / TPE);
    int f = (int)(gid - (long long)e * TPE);
    int s = src[e];
    int d = dst[e];
    const float4 v = ((const float4*)(feat + (size_t)s * D))[f];
    float* a = agg + (size_t)d * D + f * 4;
    atomicAdd(a + 0, v.x);
    atomicAdd(a + 1, v.y);
    atomicAdd(a + 2, v.z);
    atomicAdd(a + 3, v.w);
    if (cnt && f == 0) atomicAdd(cnt + d, 1.0f);
}

// ---------------------------------------------------------------------------
// Layer 1: h1 = relu(LN(agg/cnt @ Wl1 + bl1 + x @ Wr1))   [N,128]->[N,256]
// Block: 256 threads, 16 nodes. Thread t owns output column t for all 16 nodes.
// ---------------------------------------------------------------------------
__global__ __launch_bounds__(256)
void layer1_kernel(const float* __restrict__ x, const float* __restrict__ agg,
                   const float* __restrict__ cnt,
                   const float* __restrict__ Wl, const float* __restrict__ bl,
                   const float* __restrict__ Wr,
                   const float* __restrict__ g, const float* __restrict__ be,
                   float* __restrict__ h1, int N)
{
    constexpr int TM = 16;
    __shared__ float sA[TM][128];
    __shared__ float sX[TM][128];
    __shared__ float sO[TM][256];
    const int tid = threadIdx.x;
    const int n0 = blockIdx.x * TM;

    // stage normalized agg + x rows into LDS (float4, coalesced)
    for (int i = tid; i < TM * 32; i += 256) {
        int m = i >> 5, f4 = i & 31;
        size_t node = (size_t)(n0 + m);
        float4 av = ((const float4*)(agg + node * 128))[f4];
        float inv = 1.0f / fmaxf(cnt[node], 1.0f);
        av.x *= inv; av.y *= inv; av.z *= inv; av.w *= inv;
        ((float4*)sA[m])[f4] = av;
        ((float4*)sX[m])[f4] = ((const float4*)(x + node * 128))[f4];
    }
    __syncthreads();

    const int col = tid;
    float acc[TM];
#pragma unroll
    for (int m = 0; m < TM; ++m) acc[m] = 0.f;

    for (int k = 0; k < 128; k += 4) {
        float wl0 = Wl[(k + 0) * 256 + col], wl1 = Wl[(k + 1) * 256 + col];
        float wl2 = Wl[(k + 2) * 256 + col], wl3 = Wl[(k + 3) * 256 + col];
        float wr0 = Wr[(k + 0) * 256 + col], wr1 = Wr[(k + 1) * 256 + col];
        float wr2 = Wr[(k + 2) * 256 + col], wr3 = Wr[(k + 3) * 256 + col];
#pragma unroll
        for (int m = 0; m < TM; ++m) {
            float4 a  = *(const float4*)&sA[m][k];
            float4 xv = *(const float4*)&sX[m][k];
            acc[m] += a.x * wl0 + a.y * wl1 + a.z * wl2 + a.w * wl3
                    + xv.x * wr0 + xv.y * wr1 + xv.z * wr2 + xv.w * wr3;
        }
    }
    float b = bl[col];
#pragma unroll
    for (int m = 0; m < TM; ++m) sO[m][col] = acc[m] + b;
    __syncthreads();

    // LayerNorm + ReLU: 16 threads per node
    const int m = tid >> 4, l = tid & 15;
    float s = 0.f, ss = 0.f;
#pragma unroll
    for (int c = l; c < 256; c += 16) { float v = sO[m][c]; s += v; ss += v * v; }
#pragma unroll
    for (int off = 1; off < 16; off <<= 1) {
        s  += __shfl_xor(s, off);
        ss += __shfl_xor(ss, off);
    }
    float mu  = s * (1.f / 256.f);
    float var = ss * (1.f / 256.f) - mu * mu;
    float inv = rsqrtf(var + LN_EPS);
    size_t node = (size_t)(n0 + m);
#pragma unroll
    for (int c = l; c < 256; c += 16) {
        float v = (sO[m][c] - mu) * inv * g[c] + be[c];
        h1[node * 256 + c] = fmaxf(v, 0.f);
    }
}

// ---------------------------------------------------------------------------
// Layer 2 + residual: out = relu(LN(agg2/cnt @ Wl2 + bl2 + h1 @ Wr2)) + (x @ Wres + bres)
// Block: 256 threads, 8 nodes. Reads its own h1 rows from d_out, overwrites them.
// ---------------------------------------------------------------------------
__global__ __launch_bounds__(256)
void layer2_kernel(const float* __restrict__ x, const float* __restrict__ h1,
                   const float* __restrict__ agg, const float* __restrict__ cnt,
                   const float* __restrict__ Wl, const float* __restrict__ bl,
                   const float* __restrict__ Wr,
                   const float* __restrict__ g, const float* __restrict__ be,
                   const float* __restrict__ Wres, const float* __restrict__ bres,
                   float* __restrict__ out, int N)
{
    constexpr int TM = 8;
    __shared__ float sAgg[TM][256];
    __shared__ float sH[TM][256];
    __shared__ float sX[TM][128];
    __shared__ float sO[TM][256];
    __shared__ float sB[TM][256];
    const int tid = threadIdx.x;
    const int n0 = blockIdx.x * TM;

    for (int i = tid; i < TM * 64; i += 256) {
        int m = i >> 6, f4 = i & 63;
        size_t node = (size_t)(n0 + m);
        float4 av = ((const float4*)(agg + node * 256))[f4];
        float inv = 1.0f / fmaxf(cnt[node], 1.0f);
        av.x *= inv; av.y *= inv; av.z *= inv; av.w *= inv;
        ((float4*)sAgg[m])[f4] = av;
        ((float4*)sH[m])[f4] = ((const float4*)(h1 + node * 256))[f4];
    }
    for (int i = tid; i < TM * 32; i += 256) {
        int m = i >> 5, f4 = i & 31;
        size_t node = (size_t)(n0 + m);
        ((float4*)sX[m])[f4] = ((const float4*)(x + node * 128))[f4];
    }
    __syncthreads();

    const int col = tid;
    float accS[TM], accB[TM];
#pragma unroll
    for (int m = 0; m < TM; ++m) { accS[m] = 0.f; accB[m] = 0.f; }

    for (int k = 0; k < 256; k += 4) {
        float w0 = Wl[(k + 0) * 256 + col], w1 = Wl[(k + 1) * 256 + col];
        float w2 = Wl[(k + 2) * 256 + col], w3 = Wl[(k + 3) * 256 + col];
#pragma unroll
        for (int m = 0; m < TM; ++m) {
            float4 a = *(const float4*)&sAgg[m][k];
            accS[m] += a.x * w0 + a.y * w1 + a.z * w2 + a.w * w3;
        }
    }
    for (int k = 0; k < 256; k += 4) {
        float w0 = Wr[(k + 0) * 256 + col], w1 = Wr[(k + 1) * 256 + col];
        float w2 = Wr[(k + 2) * 256 + col], w3 = Wr[(k + 3) * 256 + col];
#pragma unroll
        for (int m = 0; m < TM; ++m) {
            float4 a = *(const float4*)&sH[m][k];
            accS[m] += a.x * w0 + a.y * w1 + a.z * w2 + a.w * w3;
        }
    }
    for (int k = 0; k < 128; k += 4) {
        float w0 = Wres[(k + 0) * 256 + col], w1 = Wres[(k + 1) * 256 + col];
        float w2 = Wres[(k + 2) * 256 + col], w3 = Wres[(k + 3) * 256 + col];
#pragma unroll
        for (int m = 0; m < TM; ++m) {
            float4 a = *(const float4*)&sX[m][k];
            accB[m] += a.x * w0 + a.y * w1 + a.z * w2 + a.w * w3;
        }
    }
    float b = bl[col], bb = bres[col];
#pragma unroll
    for (int m = 0; m < TM; ++m) { sO[m][col] = accS[m] + b; sB[m][col] = accB[m] + bb; }
    __syncthreads();

    // LN + ReLU + residual: 32 threads per node
    const int m = tid >> 5, l = tid & 31;
    float s = 0.f, ss = 0.f;
#pragma unroll
    for (int c = l; c < 256; c += 32) { float v = sO[m][c]; s += v; ss += v * v; }
#pragma unroll
    for (int off = 1; off < 32; off <<= 1) {
        s  += __shfl_xor(s, off);
        ss += __shfl_xor(ss, off);
    }
    float mu  = s * (1.f / 256.f);
    float var = ss * (1.f / 256.f) - mu * mu;
    float inv = rsqrtf(var + LN_EPS);
    size_t node = (size_t)(n0 + m);
#pragma unroll
    for (int c = l; c < 256; c += 32) {
        float v = (sO[m][c] - mu) * inv * g[c] + be[c];
        out[node * 256 + c] = fmaxf(v, 0.f) + sB[m][c];
    }
}

extern "C" void kernel_launch(void* const* d_in, const int* in_sizes, int n_in,
                              void* d_out, int out_size, void* d_ws, size_t ws_size,
                              hipStream_t stream)
{
    const float* x    = (const float*)d_in[0];
    const int*   ei   = (const int*)d_in[1];
    const float* Wl1  = (const float*)d_in[2];
    const float* bl1  = (const float*)d_in[3];
    const float* Wr1  = (const float*)d_in[4];
    const float* g1   = (const float*)d_in[5];
    const float* be1  = (const float*)d_in[6];
    const float* Wl2  = (const float*)d_in[7];
    const float* bl2  = (const float*)d_in[8];
    const float* Wr2  = (const float*)d_in[9];
    const float* g2   = (const float*)d_in[10];
    const float* be2  = (const float*)d_in[11];
    const float* Wres = (const float*)d_in[12];
    const float* bres = (const float*)d_in[13];

    const int N = in_sizes[0] / 128;
    const int E = in_sizes[1] / 2;
    const int* src = ei;
    const int* dst = ei + E;

    // workspace layout: agg1 [N*128] | cnt [N] | agg2 [N*256]   (~77 MB)
    float* agg1 = (float*)d_ws;
    float* cnt  = agg1 + (size_t)N * 128;
    float* agg2 = cnt + N;

    float* h1  = (float*)d_out;   // h1 lives in d_out, overwritten in-place by layer 2
    float* out = (float*)d_out;

    size_t zero_bytes = (size_t)N * (128 + 1 + 256) * sizeof(float);
    hipMemsetAsync(d_ws, 0, zero_bytes, stream);

    {
        long long tot = (long long)E * 32;
        int blocks = (int)((tot + 255) / 256);
        scatter_add_kernel<128><<<blocks, 256, 0, stream>>>(x, src, dst, agg1, cnt, E);
    }

    layer1_kernel<<<N / 16, 256, 0, stream>>>(x, agg1, cnt, Wl1, bl1, Wr1, g1, be1, h1, N);

    {
        long long tot = (long long)E * 64;
        int blocks = (int)((tot + 255) / 256);
        scatter_add_kernel<256><<<blocks, 256, 0, stream>>>(h1, src, dst, agg2, nullptr, E);
    }

    layer2_kernel<<<N / 8, 256, 0, stream>>>(x, h1, agg2, cnt, Wl2, bl2, Wr2, g2, be2,
                                             Wres, bres, out, N);
}

// Round 2
// 849.066 us; speedup vs baseline: 5.4679x; 5.4679x over previous
//
#include <hip/hip_runtime.h>
#include <hip/hip_bf16.h>

constexpr float LN_EPS = 1e-5f;

// ---------------------------------------------------------------------------
// CSR build: degree count -> prefix scan -> bucket fill
// ---------------------------------------------------------------------------
__global__ __launch_bounds__(256)
void degree_kernel(const int* __restrict__ dst, int* __restrict__ deg, int E)
{
    int e = blockIdx.x * 256 + threadIdx.x;
    if (e < E) atomicAdd(&deg[dst[e]], 1);
}

__global__ __launch_bounds__(1024)
void scan_kernel(const int* __restrict__ deg, int* __restrict__ row_ptr,
                 int* __restrict__ offs, int N)
{
    __shared__ int part[1024];
    const int tid = threadIdx.x;
    const int chunk = (N + 1023) / 1024;
    const int beg = tid * chunk;
    const int end = min(beg + chunk, N);
    int s = 0;
    for (int i = beg; i < end; ++i) s += deg[i];
    part[tid] = s;
    __syncthreads();
    for (int off = 1; off < 1024; off <<= 1) {
        int v = (tid >= off) ? part[tid - off] : 0;
        __syncthreads();
        part[tid] += v;
        __syncthreads();
    }
    int run = (tid > 0) ? part[tid - 1] : 0;   // exclusive prefix of this chunk
    for (int i = beg; i < end; ++i) {
        row_ptr[i] = run;
        offs[i] = run;
        run += deg[i];
    }
    if (tid == 1023) row_ptr[N] = part[1023];
}

__global__ __launch_bounds__(256)
void csr_fill_kernel(const int* __restrict__ src, const int* __restrict__ dst,
                     int* __restrict__ offs, int* __restrict__ csr_src, int E)
{
    int e = blockIdx.x * 256 + threadIdx.x;
    if (e < E) {
        int p = atomicAdd(&offs[dst[e]], 1);
        csr_src[p] = src[e];
    }
}

// ---------------------------------------------------------------------------
// Layer 1 fused: mean-gather neighbors of x -> LDS, then
// h1 = relu(LN(agg @ Wl1 + bl1 + x @ Wr1))   [N,128]->[N,256]
// Block: 256 threads, 16 nodes. Thread t owns output column t for all 16 nodes.
// ---------------------------------------------------------------------------
__global__ __launch_bounds__(256)
void layer1_kernel(const float* __restrict__ x,
                   const int* __restrict__ row_ptr, const int* __restrict__ csr_src,
                   const float* __restrict__ Wl, const float* __restrict__ bl,
                   const float* __restrict__ Wr,
                   const float* __restrict__ g, const float* __restrict__ be,
                   float* __restrict__ h1, int N)
{
    constexpr int TM = 16;
    __shared__ float sA[TM][128];
    __shared__ float sX[TM][128];
    __shared__ float sO[TM][256];
    const int tid = threadIdx.x;
    const int n0 = blockIdx.x * TM;

    // gather-mean neighbor rows + stage own x rows (float4 coalesced per 32-lane group)
    for (int i = tid; i < TM * 32; i += 256) {
        int m = i >> 5, f4 = i & 31;
        int node = n0 + m;
        int beg = row_ptr[node], end = row_ptr[node + 1];
        float4 acc = make_float4(0.f, 0.f, 0.f, 0.f);
        for (int e = beg; e < end; ++e) {
            int s = csr_src[e];
            const float4 v = ((const float4*)(x + (size_t)s * 128))[f4];
            acc.x += v.x; acc.y += v.y; acc.z += v.z; acc.w += v.w;
        }
        float inv = 1.0f / fmaxf((float)(end - beg), 1.0f);
        acc.x *= inv; acc.y *= inv; acc.z *= inv; acc.w *= inv;
        ((float4*)sA[m])[f4] = acc;
        ((float4*)sX[m])[f4] = ((const float4*)(x + (size_t)node * 128))[f4];
    }
    __syncthreads();

    const int col = tid;
    float acc[TM];
#pragma unroll
    for (int m = 0; m < TM; ++m) acc[m] = 0.f;

    for (int k = 0; k < 128; k += 4) {
        float wl0 = Wl[(k + 0) * 256 + col], wl1 = Wl[(k + 1) * 256 + col];
        float wl2 = Wl[(k + 2) * 256 + col], wl3 = Wl[(k + 3) * 256 + col];
        float wr0 = Wr[(k + 0) * 256 + col], wr1 = Wr[(k + 1) * 256 + col];
        float wr2 = Wr[(k + 2) * 256 + col], wr3 = Wr[(k + 3) * 256 + col];
#pragma unroll
        for (int m = 0; m < TM; ++m) {
            float4 a  = *(const float4*)&sA[m][k];
            float4 xv = *(const float4*)&sX[m][k];
            acc[m] += a.x * wl0 + a.y * wl1 + a.z * wl2 + a.w * wl3
                    + xv.x * wr0 + xv.y * wr1 + xv.z * wr2 + xv.w * wr3;
        }
    }
    float b = bl[col];
#pragma unroll
    for (int m = 0; m < TM; ++m) sO[m][col] = acc[m] + b;
    __syncthreads();

    // LayerNorm + ReLU: 16 threads per node
    const int m = tid >> 4, l = tid & 15;
    float s = 0.f, ss = 0.f;
#pragma unroll
    for (int c = l; c < 256; c += 16) { float v = sO[m][c]; s += v; ss += v * v; }
#pragma unroll
    for (int off = 1; off < 16; off <<= 1) {
        s  += __shfl_xor(s, off);
        ss += __shfl_xor(ss, off);
    }
    float mu  = s * (1.f / 256.f);
    float var = ss * (1.f / 256.f) - mu * mu;
    float inv = rsqrtf(var + LN_EPS);
    size_t node = (size_t)(n0 + m);
#pragma unroll
    for (int c = l; c < 256; c += 16) {
        float v = (sO[m][c] - mu) * inv * g[c] + be[c];
        h1[node * 256 + c] = fmaxf(v, 0.f);
    }
}

// ---------------------------------------------------------------------------
// Layer 2 fused + residual:
// out = relu(LN(mean_gather(h1) @ Wl2 + bl2 + h1 @ Wr2)) + (x @ Wres + bres)
// Block: 256 threads, 8 nodes. h1 in ws (read-only here), out -> d_out.
// ---------------------------------------------------------------------------
__global__ __launch_bounds__(256)
void layer2_kernel(const float* __restrict__ x, const float* __restrict__ h1,
                   const int* __restrict__ row_ptr, const int* __restrict__ csr_src,
                   const float* __restrict__ Wl, const float* __restrict__ bl,
                   const float* __restrict__ Wr,
                   const float* __restrict__ g, const float* __restrict__ be,
                   const float* __restrict__ Wres, const float* __restrict__ bres,
                   float* __restrict__ out, int N)
{
    constexpr int TM = 8;
    __shared__ float sAgg[TM][256];
    __shared__ float sH[TM][256];
    __shared__ float sX[TM][128];
    __shared__ float sO[TM][256];
    __shared__ float sB[TM][256];
    const int tid = threadIdx.x;
    const int n0 = blockIdx.x * TM;

    // gather-mean neighbor h1 rows + stage own h1 rows (one wave per node: uniform loop)
    for (int i = tid; i < TM * 64; i += 256) {
        int m = i >> 6, f4 = i & 63;
        int node = n0 + m;
        int beg = row_ptr[node], end = row_ptr[node + 1];
        float4 acc = make_float4(0.f, 0.f, 0.f, 0.f);
        for (int e = beg; e < end; ++e) {
            int s = csr_src[e];
            const float4 v = ((const float4*)(h1 + (size_t)s * 256))[f4];
            acc.x += v.x; acc.y += v.y; acc.z += v.z; acc.w += v.w;
        }
        float inv = 1.0f / fmaxf((float)(end - beg), 1.0f);
        acc.x *= inv; acc.y *= inv; acc.z *= inv; acc.w *= inv;
        ((float4*)sAgg[m])[f4] = acc;
        ((float4*)sH[m])[f4] = ((const float4*)(h1 + (size_t)node * 256))[f4];
    }
    for (int i = tid; i < TM * 32; i += 256) {
        int m = i >> 5, f4 = i & 31;
        size_t node = (size_t)(n0 + m);
        ((float4*)sX[m])[f4] = ((const float4*)(x + node * 128))[f4];
    }
    __syncthreads();

    const int col = tid;
    float accS[TM], accB[TM];
#pragma unroll
    for (int m = 0; m < TM; ++m) { accS[m] = 0.f; accB[m] = 0.f; }

    for (int k = 0; k < 256; k += 4) {
        float w0 = Wl[(k + 0) * 256 + col], w1 = Wl[(k + 1) * 256 + col];
        float w2 = Wl[(k + 2) * 256 + col], w3 = Wl[(k + 3) * 256 + col];
#pragma unroll
        for (int m = 0; m < TM; ++m) {
            float4 a = *(const float4*)&sAgg[m][k];
            accS[m] += a.x * w0 + a.y * w1 + a.z * w2 + a.w * w3;
        }
    }
    for (int k = 0; k < 256; k += 4) {
        float w0 = Wr[(k + 0) * 256 + col], w1 = Wr[(k + 1) * 256 + col];
        float w2 = Wr[(k + 2) * 256 + col], w3 = Wr[(k + 3) * 256 + col];
#pragma unroll
        for (int m = 0; m < TM; ++m) {
            float4 a = *(const float4*)&sH[m][k];
            accS[m] += a.x * w0 + a.y * w1 + a.z * w2 + a.w * w3;
        }
    }
    for (int k = 0; k < 128; k += 4) {
        float w0 = Wres[(k + 0) * 256 + col], w1 = Wres[(k + 1) * 256 + col];
        float w2 = Wres[(k + 2) * 256 + col], w3 = Wres[(k + 3) * 256 + col];
#pragma unroll
        for (int m = 0; m < TM; ++m) {
            float4 a = *(const float4*)&sX[m][k];
            accB[m] += a.x * w0 + a.y * w1 + a.z * w2 + a.w * w3;
        }
    }
    float b = bl[col], bb = bres[col];
#pragma unroll
    for (int m = 0; m < TM; ++m) { sO[m][col] = accS[m] + b; sB[m][col] = accB[m] + bb; }
    __syncthreads();

    // LN + ReLU + residual: 32 threads per node
    const int m = tid >> 5, l = tid & 31;
    float s = 0.f, ss = 0.f;
#pragma unroll
    for (int c = l; c < 256; c += 32) { float v = sO[m][c]; s += v; ss += v * v; }
#pragma unroll
    for (int off = 1; off < 32; off <<= 1) {
        s  += __shfl_xor(s, off);
        ss += __shfl_xor(ss, off);
    }
    float mu  = s * (1.f / 256.f);
    float var = ss * (1.f / 256.f) - mu * mu;
    float inv = rsqrtf(var + LN_EPS);
    size_t node = (size_t)(n0 + m);
#pragma unroll
    for (int c = l; c < 256; c += 32) {
        float v = (sO[m][c] - mu) * inv * g[c] + be[c];
        out[node * 256 + c] = fmaxf(v, 0.f) + sB[m][c];
    }
}

extern "C" void kernel_launch(void* const* d_in, const int* in_sizes, int n_in,
                              void* d_out, int out_size, void* d_ws, size_t ws_size,
                              hipStream_t stream)
{
    const float* x    = (const float*)d_in[0];
    const int*   ei   = (const int*)d_in[1];
    const float* Wl1  = (const float*)d_in[2];
    const float* bl1  = (const float*)d_in[3];
    const float* Wr1  = (const float*)d_in[4];
    const float* g1   = (const float*)d_in[5];
    const float* be1  = (const float*)d_in[6];
    const float* Wl2  = (const float*)d_in[7];
    const float* bl2  = (const float*)d_in[8];
    const float* Wr2  = (const float*)d_in[9];
    const float* g2   = (const float*)d_in[10];
    const float* be2  = (const float*)d_in[11];
    const float* Wres = (const float*)d_in[12];
    const float* bres = (const float*)d_in[13];

    const int N = in_sizes[0] / 128;
    const int E = in_sizes[1] / 2;
    const int* src = ei;
    const int* dst = ei + E;

    // workspace layout:
    //   h1      : N*256 floats (51.2 MB, 16B aligned at base)
    //   deg     : N ints
    //   row_ptr : N+1 ints
    //   offs    : N ints
    //   csr_src : E ints
    float* h1      = (float*)d_ws;
    int*   deg     = (int*)(h1 + (size_t)N * 256);
    int*   row_ptr = deg + N;
    int*   offs    = row_ptr + (N + 1);
    int*   csr_src = offs + N;

    hipMemsetAsync(deg, 0, (size_t)N * sizeof(int), stream);

    int eb = (E + 255) / 256;
    degree_kernel<<<eb, 256, 0, stream>>>(dst, deg, E);
    scan_kernel<<<1, 1024, 0, stream>>>(deg, row_ptr, offs, N);
    csr_fill_kernel<<<eb, 256, 0, stream>>>(src, dst, offs, csr_src, E);

    layer1_kernel<<<N / 16, 256, 0, stream>>>(x, row_ptr, csr_src,
                                              Wl1, bl1, Wr1, g1, be1, h1, N);

    layer2_kernel<<<N / 8, 256, 0, stream>>>(x, h1, row_ptr, csr_src,
                                             Wl2, bl2, Wr2, g2, be2,
                                             Wres, bres, (float*)d_out, N);
}

// Round 3
// 507.476 us; speedup vs baseline: 9.1485x; 1.6731x over previous
//
#include <hip/hip_runtime.h>

typedef short short8v __attribute__((ext_vector_type(8)));   // 8 bf16 (4 VGPRs)
typedef float f32x4  __attribute__((ext_vector_type(4)));    // MFMA acc

constexpr float LN_EPS = 1e-5f;

__device__ inline unsigned short f2bf(float f) {
    unsigned u = __float_as_uint(f);
    u += 0x7fffu + ((u >> 16) & 1u);          // RTN-even
    return (unsigned short)(u >> 16);
}
__device__ inline unsigned pack2(float lo, float hi) {
    return (unsigned)f2bf(lo) | ((unsigned)f2bf(hi) << 16);
}
__device__ inline float bflo(unsigned u) { return __uint_as_float(u << 16); }
__device__ inline float bfhi(unsigned u) { return __uint_as_float(u & 0xffff0000u); }

// ---------------------------------------------------------------------------
// CSR build
// ---------------------------------------------------------------------------
__global__ __launch_bounds__(256)
void degree_kernel(const int* __restrict__ dst, int* __restrict__ deg, int E)
{
    int e = blockIdx.x * 256 + threadIdx.x;
    if (e < E) atomicAdd(&deg[dst[e]], 1);
}

__global__ __launch_bounds__(1024)
void scan_kernel(const int* __restrict__ deg, int* __restrict__ row_ptr,
                 int* __restrict__ offs, int N)
{
    __shared__ int part[1024];
    const int tid = threadIdx.x;
    const int chunk = (N + 1023) / 1024;
    const int beg = tid * chunk;
    const int end = min(beg + chunk, N);
    int s = 0;
    for (int i = beg; i < end; ++i) s += deg[i];
    part[tid] = s;
    __syncthreads();
    for (int off = 1; off < 1024; off <<= 1) {
        int v = (tid >= off) ? part[tid - off] : 0;
        __syncthreads();
        part[tid] += v;
        __syncthreads();
    }
    int run = (tid > 0) ? part[tid - 1] : 0;
    for (int i = beg; i < end; ++i) {
        row_ptr[i] = run;
        offs[i] = run;
        run += deg[i];
    }
    if (tid == 1023) row_ptr[N] = part[1023];
}

__global__ __launch_bounds__(256)
void csr_fill_kernel(const int* __restrict__ src, const int* __restrict__ dst,
                     int* __restrict__ offs, int* __restrict__ csr_src, int E)
{
    int e = blockIdx.x * 256 + threadIdx.x;
    if (e < E) {
        int p = atomicAdd(&offs[dst[e]], 1);
        csr_src[p] = src[e];
    }
}

// ---------------------------------------------------------------------------
// x fp32 -> bf16 into Acat1 cols 128..255 (uints 64..127 of the 128-uint row)
// ---------------------------------------------------------------------------
__global__ __launch_bounds__(256)
void prep_x_kernel(const float* __restrict__ x, unsigned* __restrict__ acat1, int N)
{
    int t = blockIdx.x * 256 + threadIdx.x;       // one per 2 floats, N*64 total
    if (t >= N * 64) return;
    int row = t >> 6, c = t & 63;
    float2 v = ((const float2*)x)[t];
    acat1[(size_t)row * 128 + 64 + c] = pack2(v.x, v.y);
}

// ---------------------------------------------------------------------------
// Pack fp32 weights (row-major K x 256, concat of up to 3 sources) into MFMA
// B-fragment layout: frag (kt,nt) is 64 lanes x 8 bf16;
//   lane l holds col j = nt*16+(l&15), k = kt*32+(l>>4)*8+e.
// ---------------------------------------------------------------------------
__global__ __launch_bounds__(256)
void pack_w_kernel(const float* __restrict__ WA, int ka,
                   const float* __restrict__ WB, int kb,
                   const float* __restrict__ WC,
                   unsigned short* __restrict__ out, int K)
{
    int t = blockIdx.x * 256 + threadIdx.x;       // t = ((kt*16)+nt)*64 + lane
    int total = (K / 32) * 16 * 64;
    if (t >= total) return;
    int lane = t & 63;
    int nt = (t >> 6) & 15;
    int kt = t >> 10;
    int j = nt * 16 + (lane & 15);
    unsigned short* o = out + (size_t)t * 8;
#pragma unroll
    for (int e = 0; e < 8; ++e) {
        int k = kt * 32 + ((lane >> 4) & 3) * 8 + e;
        float v;
        if (k < ka)      v = WA[(size_t)k * 256 + j];
        else if (k < kb) v = WB[(size_t)(k - ka) * 256 + j];
        else             v = WC[(size_t)(k - kb) * 256 + j];
        o[e] = f2bf(v);
    }
}

// ---------------------------------------------------------------------------
// Gather-mean of x_bf (Acat1 cols 128..255) -> Acat1 cols 0..127. Wave/node.
// ---------------------------------------------------------------------------
__global__ __launch_bounds__(256)
void gather1_kernel(const int* __restrict__ row_ptr, const int* __restrict__ csr_src,
                    unsigned* __restrict__ acat1, int N)
{
    int node = blockIdx.x * 4 + (threadIdx.x >> 6);
    int lane = threadIdx.x & 63;
    if (node >= N) return;
    int beg = row_ptr[node], end = row_ptr[node + 1];
    float a0 = 0.f, a1 = 0.f;
    for (int e = beg; e < end; ++e) {
        int s = csr_src[e];
        unsigned u = acat1[(size_t)s * 128 + 64 + lane];
        a0 += bflo(u); a1 += bfhi(u);
    }
    float inv = 1.0f / fmaxf((float)(end - beg), 1.0f);
    acat1[(size_t)node * 128 + lane] = pack2(a0 * inv, a1 * inv);
}

// ---------------------------------------------------------------------------
// Gather-mean of h1_bf (Acat2 cols 256..511) -> Acat2 cols 0..255. Wave/node.
// ---------------------------------------------------------------------------
__global__ __launch_bounds__(256)
void gather2_kernel(const int* __restrict__ row_ptr, const int* __restrict__ csr_src,
                    unsigned* __restrict__ acat2, int N)
{
    int node = blockIdx.x * 4 + (threadIdx.x >> 6);
    int lane = threadIdx.x & 63;
    if (node >= N) return;
    int beg = row_ptr[node], end = row_ptr[node + 1];
    float a0 = 0.f, a1 = 0.f, a2 = 0.f, a3 = 0.f;
    for (int e = beg; e < end; ++e) {
        int s = csr_src[e];
        const unsigned* h = acat2 + (size_t)s * 256 + 128;
        unsigned u0 = h[lane];
        unsigned u1 = h[64 + lane];
        a0 += bflo(u0); a1 += bfhi(u0);
        a2 += bflo(u1); a3 += bfhi(u1);
    }
    float inv = 1.0f / fmaxf((float)(end - beg), 1.0f);
    acat2[(size_t)node * 256 + lane]      = pack2(a0 * inv, a1 * inv);
    acat2[(size_t)node * 256 + 64 + lane] = pack2(a2 * inv, a3 * inv);
}

// ---------------------------------------------------------------------------
// GEMM1: h1 = relu(LN(Acat1[N,256] @ W1[256,256] + bl)) -> bf16 into Acat2 cols 256..511
// Block = 256 thr = 4 waves; wave owns 16 rows x 256 cols; no LDS, no K-loop barriers.
// ---------------------------------------------------------------------------
__global__ __launch_bounds__(256)
void gemm1_kernel(const short8v* __restrict__ A,     // Acat1: 32 frags per row
                  const short8v* __restrict__ Bpk,   // Wpk1: (kt*16+nt)*64+lane
                  const float* __restrict__ bl, const float* __restrict__ g,
                  const float* __restrict__ be,
                  unsigned short* __restrict__ h1out, // Acat2 ushort view, stride 512
                  int N)
{
    const int lane = threadIdx.x & 63;
    const int wave = threadIdx.x >> 6;
    const int rbase = blockIdx.x * 64 + wave * 16;
    int arow = rbase + (lane & 15);
    if (arow >= N) arow = N - 1;
    const short8v* Ar = A + (size_t)arow * 32 + (lane >> 4);

    f32x4 acc[16];
#pragma unroll
    for (int nt = 0; nt < 16; ++nt) acc[nt] = (f32x4){0.f, 0.f, 0.f, 0.f};

#pragma unroll
    for (int kt = 0; kt < 8; ++kt) {
        short8v a = Ar[kt * 4];
        const short8v* Bp = Bpk + (size_t)(kt * 16) * 64 + lane;
#pragma unroll
        for (int nt = 0; nt < 16; ++nt)
            acc[nt] = __builtin_amdgcn_mfma_f32_16x16x32_bf16(a, Bp[(size_t)nt * 64], acc[nt], 0, 0, 0);
    }

    // epilogue: +bias, LN over 256 cols (16-lane groups hold one row set), relu, bf16
    const int col0 = lane & 15;
    const int grp  = lane >> 4;                 // rows grp*4 + r
    float s[4] = {0,0,0,0}, ss[4] = {0,0,0,0};
#pragma unroll
    for (int nt = 0; nt < 16; ++nt) {
        float blv = bl[nt * 16 + col0];
#pragma unroll
        for (int r = 0; r < 4; ++r) {
            float v = acc[nt][r] + blv;
            acc[nt][r] = v;
            s[r] += v; ss[r] += v * v;
        }
    }
#pragma unroll
    for (int off = 1; off < 16; off <<= 1) {
#pragma unroll
        for (int r = 0; r < 4; ++r) {
            s[r]  += __shfl_xor(s[r],  off);
            ss[r] += __shfl_xor(ss[r], off);
        }
    }
    float mu[4], inv[4];
#pragma unroll
    for (int r = 0; r < 4; ++r) {
        mu[r] = s[r] * (1.f / 256.f);
        float var = ss[r] * (1.f / 256.f) - mu[r] * mu[r];
        inv[r] = rsqrtf(var + LN_EPS);
    }
#pragma unroll
    for (int nt = 0; nt < 16; ++nt) {
        int col = nt * 16 + col0;
        float gv = g[col], bv = be[col];
#pragma unroll
        for (int r = 0; r < 4; ++r) {
            int srow = rbase + grp * 4 + r;
            if (srow < N) {
                float v = (acc[nt][r] - mu[r]) * inv[r] * gv + bv;
                h1out[(size_t)srow * 512 + 256 + col] = f2bf(fmaxf(v, 0.f));
            }
        }
    }
}

// ---------------------------------------------------------------------------
// GEMM2: out = relu(LN(Acat2[N,512] @ W2[0:512] + bl2)) + (x_bf @ Wres + bres)
// x_bf read from Acat1 cols 128..255; Wres = Wpk2 kt 16..19. fp32 out.
// ---------------------------------------------------------------------------
__global__ __launch_bounds__(256)
void gemm2_kernel(const short8v* __restrict__ A2,    // Acat2: 64 frags per row
                  const short8v* __restrict__ A1,    // Acat1: 32 frags per row
                  const short8v* __restrict__ Bpk,   // Wpk2: 20 kt
                  const float* __restrict__ bl, const float* __restrict__ g,
                  const float* __restrict__ be, const float* __restrict__ bres,
                  float* __restrict__ out, int N)
{
    const int lane = threadIdx.x & 63;
    const int wave = threadIdx.x >> 6;
    const int rbase = blockIdx.x * 64 + wave * 16;
    int arow = rbase + (lane & 15);
    if (arow >= N) arow = N - 1;
    const short8v* Ar2 = A2 + (size_t)arow * 64 + (lane >> 4);
    const short8v* Ar1 = A1 + (size_t)arow * 32 + 16 + (lane >> 4);

    f32x4 accs[16], accb[16];
#pragma unroll
    for (int nt = 0; nt < 16; ++nt) {
        accs[nt] = (f32x4){0.f, 0.f, 0.f, 0.f};
        accb[nt] = (f32x4){0.f, 0.f, 0.f, 0.f};
    }

#pragma unroll
    for (int kt = 0; kt < 16; ++kt) {
        short8v a = Ar2[kt * 4];
        const short8v* Bp = Bpk + (size_t)(kt * 16) * 64 + lane;
#pragma unroll
        for (int nt = 0; nt < 16; ++nt)
            accs[nt] = __builtin_amdgcn_mfma_f32_16x16x32_bf16(a, Bp[(size_t)nt * 64], accs[nt], 0, 0, 0);
    }
#pragma unroll
    for (int kt = 0; kt < 4; ++kt) {
        short8v a = Ar1[kt * 4];
        const short8v* Bp = Bpk + (size_t)((16 + kt) * 16) * 64 + lane;
#pragma unroll
        for (int nt = 0; nt < 16; ++nt)
            accb[nt] = __builtin_amdgcn_mfma_f32_16x16x32_bf16(a, Bp[(size_t)nt * 64], accb[nt], 0, 0, 0);
    }

    const int col0 = lane & 15;
    const int grp  = lane >> 4;
    float s[4] = {0,0,0,0}, ss[4] = {0,0,0,0};
#pragma unroll
    for (int nt = 0; nt < 16; ++nt) {
        float blv = bl[nt * 16 + col0];
#pragma unroll
        for (int r = 0; r < 4; ++r) {
            float v = accs[nt][r] + blv;
            accs[nt][r] = v;
            s[r] += v; ss[r] += v * v;
        }
    }
#pragma unroll
    for (int off = 1; off < 16; off <<= 1) {
#pragma unroll
        for (int r = 0; r < 4; ++r) {
            s[r]  += __shfl_xor(s[r],  off);
            ss[r] += __shfl_xor(ss[r], off);
        }
    }
    float mu[4], inv[4];
#pragma unroll
    for (int r = 0; r < 4; ++r) {
        mu[r] = s[r] * (1.f / 256.f);
        float var = ss[r] * (1.f / 256.f) - mu[r] * mu[r];
        inv[r] = rsqrtf(var + LN_EPS);
    }
#pragma unroll
    for (int nt = 0; nt < 16; ++nt) {
        int col = nt * 16 + col0;
        float gv = g[col], bv = be[col], brv = bres[col];
#pragma unroll
        for (int r = 0; r < 4; ++r) {
            int srow = rbase + grp * 4 + r;
            if (srow < N) {
                float v = (accs[nt][r] - mu[r]) * inv[r] * gv + bv;
                out[(size_t)srow * 256 + col] = fmaxf(v, 0.f) + accb[nt][r] + brv;
            }
        }
    }
}

extern "C" void kernel_launch(void* const* d_in, const int* in_sizes, int n_in,
                              void* d_out, int out_size, void* d_ws, size_t ws_size,
                              hipStream_t stream)
{
    const float* x    = (const float*)d_in[0];
    const int*   ei   = (const int*)d_in[1];
    const float* Wl1  = (const float*)d_in[2];
    const float* bl1  = (const float*)d_in[3];
    const float* Wr1  = (const float*)d_in[4];
    const float* g1   = (const float*)d_in[5];
    const float* be1  = (const float*)d_in[6];
    const float* Wl2  = (const float*)d_in[7];
    const float* bl2  = (const float*)d_in[8];
    const float* Wr2  = (const float*)d_in[9];
    const float* g2   = (const float*)d_in[10];
    const float* be2  = (const float*)d_in[11];
    const float* Wres = (const float*)d_in[12];
    const float* bres = (const float*)d_in[13];

    const int N = in_sizes[0] / 128;
    const int E = in_sizes[1] / 2;
    const int* src = ei;
    const int* dst = ei + E;

    // ws layout (bytes): Acat1 N*256 bf16 | Acat2 N*512 bf16 | Wpk1 256*256 bf16
    //                    | Wpk2 640*256 bf16 | deg N | row_ptr N+1 | offs N | csr_src E
    unsigned short* acat1 = (unsigned short*)d_ws;                 // 16B aligned
    unsigned short* acat2 = acat1 + (size_t)N * 256;
    unsigned short* wpk1  = acat2 + (size_t)N * 512;
    unsigned short* wpk2  = wpk1 + 256 * 256;
    int* deg     = (int*)(wpk2 + 640 * 256);
    int* row_ptr = deg + N;
    int* offs    = row_ptr + (N + 1);
    int* csr_src = offs + N;

    hipMemsetAsync(deg, 0, (size_t)N * sizeof(int), stream);

    const int eb = (E + 255) / 256;
    degree_kernel<<<eb, 256, 0, stream>>>(dst, deg, E);
    scan_kernel<<<1, 1024, 0, stream>>>(deg, row_ptr, offs, N);
    csr_fill_kernel<<<eb, 256, 0, stream>>>(src, dst, offs, csr_src, E);

    prep_x_kernel<<<(N * 64 + 255) / 256, 256, 0, stream>>>(x, (unsigned*)acat1, N);
    pack_w_kernel<<<(8 * 16 * 64 + 255) / 256, 256, 0, stream>>>(Wl1, 128, Wr1, 256, Wr1, wpk1, 256);
    pack_w_kernel<<<(20 * 16 * 64 + 255) / 256, 256, 0, stream>>>(Wl2, 256, Wr2, 512, Wres, wpk2, 640);

    gather1_kernel<<<(N + 3) / 4, 256, 0, stream>>>(row_ptr, csr_src, (unsigned*)acat1, N);

    const int gb = (N + 63) / 64;
    gemm1_kernel<<<gb, 256, 0, stream>>>((const short8v*)acat1, (const short8v*)wpk1,
                                         bl1, g1, be1, acat2, N);

    gather2_kernel<<<(N + 3) / 4, 256, 0, stream>>>(row_ptr, csr_src, (unsigned*)acat2, N);

    gemm2_kernel<<<gb, 256, 0, stream>>>((const short8v*)acat2, (const short8v*)acat1,
                                         (const short8v*)wpk2, bl2, g2, be2, bres,
                                         (float*)d_out, N);
}

// Round 4
// 425.693 us; speedup vs baseline: 10.9061x; 1.1921x over previous
//
#include <hip/hip_runtime.h>

typedef short short8v __attribute__((ext_vector_type(8)));   // 8 bf16 (4 VGPRs)
typedef float f32x4  __attribute__((ext_vector_type(4)));    // MFMA acc

constexpr float LN_EPS = 1e-5f;

__device__ inline unsigned short f2bf(float f) {
    unsigned u = __float_as_uint(f);
    u += 0x7fffu + ((u >> 16) & 1u);          // RTN-even
    return (unsigned short)(u >> 16);
}
__device__ inline unsigned pack2(float lo, float hi) {
    return (unsigned)f2bf(lo) | ((unsigned)f2bf(hi) << 16);
}
__device__ inline float bflo(unsigned u) { return __uint_as_float(u << 16); }
__device__ inline float bfhi(unsigned u) { return __uint_as_float(u & 0xffff0000u); }

// ---------------------------------------------------------------------------
// CSR build
// ---------------------------------------------------------------------------
__global__ __launch_bounds__(256)
void degree_kernel(const int* __restrict__ dst, int* __restrict__ deg, int E)
{
    int e = blockIdx.x * 256 + threadIdx.x;
    if (e < E) atomicAdd(&deg[dst[e]], 1);
}

__global__ __launch_bounds__(1024)
void scan_kernel(const int* __restrict__ deg, int* __restrict__ row_ptr,
                 int* __restrict__ offs, int N)
{
    __shared__ int part[1024];
    const int tid = threadIdx.x;
    const int chunk = (N + 1023) / 1024;
    const int beg = tid * chunk;
    const int end = min(beg + chunk, N);
    int s = 0;
    for (int i = beg; i < end; ++i) s += deg[i];
    part[tid] = s;
    __syncthreads();
    for (int off = 1; off < 1024; off <<= 1) {
        int v = (tid >= off) ? part[tid - off] : 0;
        __syncthreads();
        part[tid] += v;
        __syncthreads();
    }
    int run = (tid > 0) ? part[tid - 1] : 0;
    for (int i = beg; i < end; ++i) {
        row_ptr[i] = run;
        offs[i] = run;
        run += deg[i];
    }
    if (tid == 1023) row_ptr[N] = part[1023];
}

__global__ __launch_bounds__(256)
void csr_fill_kernel(const int* __restrict__ src, const int* __restrict__ dst,
                     int* __restrict__ offs, int* __restrict__ csr_src, int E)
{
    int e = blockIdx.x * 256 + threadIdx.x;
    if (e < E) {
        int p = atomicAdd(&offs[dst[e]], 1);
        csr_src[p] = src[e];
    }
}

// ---------------------------------------------------------------------------
// x fp32 -> bf16 into Acat1 cols 128..255 (uints 64..127 of the 128-uint row)
// ---------------------------------------------------------------------------
__global__ __launch_bounds__(256)
void prep_x_kernel(const float* __restrict__ x, unsigned* __restrict__ acat1, int N)
{
    int t = blockIdx.x * 256 + threadIdx.x;       // one per 2 floats, N*64 total
    if (t >= N * 64) return;
    int row = t >> 6, c = t & 63;
    float2 v = ((const float2*)x)[t];
    acat1[(size_t)row * 128 + 64 + c] = pack2(v.x, v.y);
}

// ---------------------------------------------------------------------------
// Pack fp32 weights (row-major K x 256, concat of up to 3 sources) into MFMA
// B-fragment layout: frag (kt,nt) is 64 lanes x 8 bf16;
//   lane l holds col j = nt*16+(l&15), k = kt*32+(l>>4)*8+e.
// ---------------------------------------------------------------------------
__global__ __launch_bounds__(256)
void pack_w_kernel(const float* __restrict__ WA, int ka,
                   const float* __restrict__ WB, int kb,
                   const float* __restrict__ WC,
                   unsigned short* __restrict__ out, int K)
{
    int t = blockIdx.x * 256 + threadIdx.x;       // t = ((kt*16)+nt)*64 + lane
    int total = (K / 32) * 16 * 64;
    if (t >= total) return;
    int lane = t & 63;
    int nt = (t >> 6) & 15;
    int kt = t >> 10;
    int j = nt * 16 + (lane & 15);
    unsigned short* o = out + (size_t)t * 8;
#pragma unroll
    for (int e = 0; e < 8; ++e) {
        int k = kt * 32 + ((lane >> 4) & 3) * 8 + e;
        float v;
        if (k < ka)      v = WA[(size_t)k * 256 + j];
        else if (k < kb) v = WB[(size_t)(k - ka) * 256 + j];
        else             v = WC[(size_t)(k - kb) * 256 + j];
        o[e] = f2bf(v);
    }
}

// ---------------------------------------------------------------------------
// Gather-mean of x_bf (Acat1 cols 128..255) -> Acat1 cols 0..127. Wave/node.
// 2-way edge unroll: two independent row loads in flight.
// ---------------------------------------------------------------------------
__global__ __launch_bounds__(256)
void gather1_kernel(const int* __restrict__ row_ptr, const int* __restrict__ csr_src,
                    unsigned* __restrict__ acat1, int N)
{
    int node = blockIdx.x * 4 + (threadIdx.x >> 6);
    int lane = threadIdx.x & 63;
    if (node >= N) return;
    int beg = row_ptr[node], end = row_ptr[node + 1];
    float a0 = 0.f, a1 = 0.f;
    float b0 = 0.f, b1 = 0.f;
    int e = beg;
    for (; e + 1 < end; e += 2) {
        int s0 = csr_src[e], s1 = csr_src[e + 1];
        unsigned u0 = acat1[(size_t)s0 * 128 + 64 + lane];
        unsigned u1 = acat1[(size_t)s1 * 128 + 64 + lane];
        a0 += bflo(u0); a1 += bfhi(u0);
        b0 += bflo(u1); b1 += bfhi(u1);
    }
    if (e < end) {
        unsigned u = acat1[(size_t)csr_src[e] * 128 + 64 + lane];
        a0 += bflo(u); a1 += bfhi(u);
    }
    a0 += b0; a1 += b1;
    float inv = 1.0f / fmaxf((float)(end - beg), 1.0f);
    acat1[(size_t)node * 128 + lane] = pack2(a0 * inv, a1 * inv);
}

// ---------------------------------------------------------------------------
// Gather-mean of h1_bf (Acat2 cols 256..511) -> Acat2 cols 0..255. Wave/node.
// uint2 loads (512B/row in one transaction) + 2-way edge unroll.
// ---------------------------------------------------------------------------
__global__ __launch_bounds__(256)
void gather2_kernel(const int* __restrict__ row_ptr, const int* __restrict__ csr_src,
                    unsigned* __restrict__ acat2, int N)
{
    int node = blockIdx.x * 4 + (threadIdx.x >> 6);
    int lane = threadIdx.x & 63;
    if (node >= N) return;
    int beg = row_ptr[node], end = row_ptr[node + 1];
    float a0 = 0.f, a1 = 0.f, a2 = 0.f, a3 = 0.f;
    float c0 = 0.f, c1 = 0.f, c2 = 0.f, c3 = 0.f;
    int e = beg;
    for (; e + 1 < end; e += 2) {
        int s0 = csr_src[e], s1 = csr_src[e + 1];
        const uint2 u = *(const uint2*)(acat2 + (size_t)s0 * 256 + 128 + lane * 2);
        const uint2 v = *(const uint2*)(acat2 + (size_t)s1 * 256 + 128 + lane * 2);
        a0 += bflo(u.x); a1 += bfhi(u.x); a2 += bflo(u.y); a3 += bfhi(u.y);
        c0 += bflo(v.x); c1 += bfhi(v.x); c2 += bflo(v.y); c3 += bfhi(v.y);
    }
    if (e < end) {
        const uint2 u = *(const uint2*)(acat2 + (size_t)csr_src[e] * 256 + 128 + lane * 2);
        a0 += bflo(u.x); a1 += bfhi(u.x); a2 += bflo(u.y); a3 += bfhi(u.y);
    }
    a0 += c0; a1 += c1; a2 += c2; a3 += c3;
    float inv = 1.0f / fmaxf((float)(end - beg), 1.0f);
    uint2 o;
    o.x = pack2(a0 * inv, a1 * inv);
    o.y = pack2(a2 * inv, a3 * inv);
    *(uint2*)(acat2 + (size_t)node * 256 + lane * 2) = o;
}

// ---------------------------------------------------------------------------
// GEMM1: h1 = relu(LN(Acat1[N,256] @ W1[256,256] + bl)) -> bf16 into Acat2 cols 256..511
// Block = 4 waves over 16 rows; wave owns cols wave*64..+63 (4 nt tiles).
// LN partial sums cross waves via tiny LDS.
// ---------------------------------------------------------------------------
__global__ __launch_bounds__(256, 4)
void gemm1_kernel(const short8v* __restrict__ A,     // Acat1: 32 frags per row
                  const short8v* __restrict__ Bpk,   // Wpk1: (kt*16+nt)*64+lane
                  const float* __restrict__ bl, const float* __restrict__ g,
                  const float* __restrict__ be,
                  unsigned short* __restrict__ h1out, // Acat2 ushort view, stride 512
                  int N)
{
    __shared__ float sS[4][16], sSS[4][16];
    const int lane = threadIdx.x & 63;
    const int wave = threadIdx.x >> 6;
    const int rbase = blockIdx.x * 16;
    int arow = rbase + (lane & 15);
    if (arow >= N) arow = N - 1;
    const short8v* Ar = A + (size_t)arow * 32 + (lane >> 4);

    f32x4 acc[4];
#pragma unroll
    for (int nt = 0; nt < 4; ++nt) acc[nt] = (f32x4){0.f, 0.f, 0.f, 0.f};

#pragma unroll
    for (int kt = 0; kt < 8; ++kt) {
        short8v a = Ar[kt * 4];
        const short8v* Bp = Bpk + (size_t)(kt * 16 + wave * 4) * 64 + lane;
#pragma unroll
        for (int nt = 0; nt < 4; ++nt)
            acc[nt] = __builtin_amdgcn_mfma_f32_16x16x32_bf16(a, Bp[(size_t)nt * 64], acc[nt], 0, 0, 0);
    }

    const int col0 = lane & 15;
    const int grp  = lane >> 4;                 // rows grp*4 + r
    float s[4] = {0,0,0,0}, ss[4] = {0,0,0,0};
#pragma unroll
    for (int nt = 0; nt < 4; ++nt) {
        float blv = bl[(wave * 4 + nt) * 16 + col0];
#pragma unroll
        for (int r = 0; r < 4; ++r) {
            float v = acc[nt][r] + blv;
            acc[nt][r] = v;
            s[r] += v; ss[r] += v * v;
        }
    }
#pragma unroll
    for (int off = 1; off < 16; off <<= 1) {
#pragma unroll
        for (int r = 0; r < 4; ++r) {
            s[r]  += __shfl_xor(s[r],  off);
            ss[r] += __shfl_xor(ss[r], off);
        }
    }
    if (col0 == 0) {
#pragma unroll
        for (int r = 0; r < 4; ++r) {
            sS[wave][grp * 4 + r]  = s[r];
            sSS[wave][grp * 4 + r] = ss[r];
        }
    }
    __syncthreads();
    float mu[4], inv[4];
#pragma unroll
    for (int r = 0; r < 4; ++r) {
        int row = grp * 4 + r;
        float S  = sS[0][row] + sS[1][row] + sS[2][row] + sS[3][row];
        float SS = sSS[0][row] + sSS[1][row] + sSS[2][row] + sSS[3][row];
        mu[r] = S * (1.f / 256.f);
        float var = SS * (1.f / 256.f) - mu[r] * mu[r];
        inv[r] = rsqrtf(var + LN_EPS);
    }
#pragma unroll
    for (int nt = 0; nt < 4; ++nt) {
        int col = (wave * 4 + nt) * 16 + col0;
        float gv = g[col], bv = be[col];
#pragma unroll
        for (int r = 0; r < 4; ++r) {
            int srow = rbase + grp * 4 + r;
            if (srow < N) {
                float v = (acc[nt][r] - mu[r]) * inv[r] * gv + bv;
                h1out[(size_t)srow * 512 + 256 + col] = f2bf(fmaxf(v, 0.f));
            }
        }
    }
}

// ---------------------------------------------------------------------------
// GEMM2: out = relu(LN(Acat2[N,512] @ W2[0:512] + bl2)) + (x_bf @ Wres + bres)
// Same 4-wave col-split; x_bf from Acat1 cols 128..255; Wres = Wpk2 kt 16..19.
// ---------------------------------------------------------------------------
__global__ __launch_bounds__(256, 4)
void gemm2_kernel(const short8v* __restrict__ A2,    // Acat2: 64 frags per row
                  const short8v* __restrict__ A1,    // Acat1: 32 frags per row
                  const short8v* __restrict__ Bpk,   // Wpk2: 20 kt
                  const float* __restrict__ bl, const float* __restrict__ g,
                  const float* __restrict__ be, const float* __restrict__ bres,
                  float* __restrict__ out, int N)
{
    __shared__ float sS[4][16], sSS[4][16];
    const int lane = threadIdx.x & 63;
    const int wave = threadIdx.x >> 6;
    const int rbase = blockIdx.x * 16;
    int arow = rbase + (lane & 15);
    if (arow >= N) arow = N - 1;
    const short8v* Ar2 = A2 + (size_t)arow * 64 + (lane >> 4);
    const short8v* Ar1 = A1 + (size_t)arow * 32 + 16 + (lane >> 4);

    f32x4 accs[4], accb[4];
#pragma unroll
    for (int nt = 0; nt < 4; ++nt) {
        accs[nt] = (f32x4){0.f, 0.f, 0.f, 0.f};
        accb[nt] = (f32x4){0.f, 0.f, 0.f, 0.f};
    }

#pragma unroll
    for (int kt = 0; kt < 16; ++kt) {
        short8v a = Ar2[kt * 4];
        const short8v* Bp = Bpk + (size_t)(kt * 16 + wave * 4) * 64 + lane;
#pragma unroll
        for (int nt = 0; nt < 4; ++nt)
            accs[nt] = __builtin_amdgcn_mfma_f32_16x16x32_bf16(a, Bp[(size_t)nt * 64], accs[nt], 0, 0, 0);
    }
#pragma unroll
    for (int kt = 0; kt < 4; ++kt) {
        short8v a = Ar1[kt * 4];
        const short8v* Bp = Bpk + (size_t)((16 + kt) * 16 + wave * 4) * 64 + lane;
#pragma unroll
        for (int nt = 0; nt < 4; ++nt)
            accb[nt] = __builtin_amdgcn_mfma_f32_16x16x32_bf16(a, Bp[(size_t)nt * 64], accb[nt], 0, 0, 0);
    }

    const int col0 = lane & 15;
    const int grp  = lane >> 4;
    float s[4] = {0,0,0,0}, ss[4] = {0,0,0,0};
#pragma unroll
    for (int nt = 0; nt < 4; ++nt) {
        float blv = bl[(wave * 4 + nt) * 16 + col0];
#pragma unroll
        for (int r = 0; r < 4; ++r) {
            float v = accs[nt][r] + blv;
            accs[nt][r] = v;
            s[r] += v; ss[r] += v * v;
        }
    }
#pragma unroll
    for (int off = 1; off < 16; off <<= 1) {
#pragma unroll
        for (int r = 0; r < 4; ++r) {
            s[r]  += __shfl_xor(s[r],  off);
            ss[r] += __shfl_xor(ss[r], off);
        }
    }
    if (col0 == 0) {
#pragma unroll
        for (int r = 0; r < 4; ++r) {
            sS[wave][grp * 4 + r]  = s[r];
            sSS[wave][grp * 4 + r] = ss[r];
        }
    }
    __syncthreads();
    float mu[4], inv[4];
#pragma unroll
    for (int r = 0; r < 4; ++r) {
        int row = grp * 4 + r;
        float S  = sS[0][row] + sS[1][row] + sS[2][row] + sS[3][row];
        float SS = sSS[0][row] + sSS[1][row] + sSS[2][row] + sSS[3][row];
        mu[r] = S * (1.f / 256.f);
        float var = SS * (1.f / 256.f) - mu[r] * mu[r];
        inv[r] = rsqrtf(var + LN_EPS);
    }
#pragma unroll
    for (int nt = 0; nt < 4; ++nt) {
        int col = (wave * 4 + nt) * 16 + col0;
        float gv = g[col], bv = be[col], brv = bres[col];
#pragma unroll
        for (int r = 0; r < 4; ++r) {
            int srow = rbase + grp * 4 + r;
            if (srow < N) {
                float v = (accs[nt][r] - mu[r]) * inv[r] * gv + bv;
                out[(size_t)srow * 256 + col] = fmaxf(v, 0.f) + accb[nt][r] + brv;
            }
        }
    }
}

extern "C" void kernel_launch(void* const* d_in, const int* in_sizes, int n_in,
                              void* d_out, int out_size, void* d_ws, size_t ws_size,
                              hipStream_t stream)
{
    const float* x    = (const float*)d_in[0];
    const int*   ei   = (const int*)d_in[1];
    const float* Wl1  = (const float*)d_in[2];
    const float* bl1  = (const float*)d_in[3];
    const float* Wr1  = (const float*)d_in[4];
    const float* g1   = (const float*)d_in[5];
    const float* be1  = (const float*)d_in[6];
    const float* Wl2  = (const float*)d_in[7];
    const float* bl2  = (const float*)d_in[8];
    const float* Wr2  = (const float*)d_in[9];
    const float* g2   = (const float*)d_in[10];
    const float* be2  = (const float*)d_in[11];
    const float* Wres = (const float*)d_in[12];
    const float* bres = (const float*)d_in[13];

    const int N = in_sizes[0] / 128;
    const int E = in_sizes[1] / 2;
    const int* src = ei;
    const int* dst = ei + E;

    // ws layout: Acat1 N*256 bf16 | Acat2 N*512 bf16 | Wpk1 256*256 bf16
    //            | Wpk2 640*256 bf16 | deg N | row_ptr N+1 | offs N | csr_src E
    unsigned short* acat1 = (unsigned short*)d_ws;
    unsigned short* acat2 = acat1 + (size_t)N * 256;
    unsigned short* wpk1  = acat2 + (size_t)N * 512;
    unsigned short* wpk2  = wpk1 + 256 * 256;
    int* deg     = (int*)(wpk2 + 640 * 256);
    int* row_ptr = deg + N;
    int* offs    = row_ptr + (N + 1);
    int* csr_src = offs + N;

    hipMemsetAsync(deg, 0, (size_t)N * sizeof(int), stream);

    const int eb = (E + 255) / 256;
    degree_kernel<<<eb, 256, 0, stream>>>(dst, deg, E);
    scan_kernel<<<1, 1024, 0, stream>>>(deg, row_ptr, offs, N);
    csr_fill_kernel<<<eb, 256, 0, stream>>>(src, dst, offs, csr_src, E);

    prep_x_kernel<<<(N * 64 + 255) / 256, 256, 0, stream>>>(x, (unsigned*)acat1, N);
    pack_w_kernel<<<(8 * 16 * 64 + 255) / 256, 256, 0, stream>>>(Wl1, 128, Wr1, 256, Wr1, wpk1, 256);
    pack_w_kernel<<<(20 * 16 * 64 + 255) / 256, 256, 0, stream>>>(Wl2, 256, Wr2, 512, Wres, wpk2, 640);

    gather1_kernel<<<(N + 3) / 4, 256, 0, stream>>>(row_ptr, csr_src, (unsigned*)acat1, N);

    const int gb = (N + 15) / 16;
    gemm1_kernel<<<gb, 256, 0, stream>>>((const short8v*)acat1, (const short8v*)wpk1,
                                         bl1, g1, be1, acat2, N);

    gather2_kernel<<<(N + 3) / 4, 256, 0, stream>>>(row_ptr, csr_src, (unsigned*)acat2, N);

    gemm2_kernel<<<gb, 256, 0, stream>>>((const short8v*)acat2, (const short8v*)acat1,
                                         (const short8v*)wpk2, bl2, g2, be2, bres,
                                         (float*)d_out, N);
}

// Round 5
// 325.265 us; speedup vs baseline: 14.2734x; 1.3088x over previous
//
#include <hip/hip_runtime.h>

typedef short short8v __attribute__((ext_vector_type(8)));   // 8 bf16 (4 VGPRs)
typedef float f32x4  __attribute__((ext_vector_type(4)));    // MFMA acc

constexpr float LN_EPS = 1e-5f;

__device__ inline unsigned short f2bf(float f) {
    unsigned u = __float_as_uint(f);
    u += 0x7fffu + ((u >> 16) & 1u);          // RTN-even
    return (unsigned short)(u >> 16);
}
__device__ inline unsigned pack2(float lo, float hi) {
    return (unsigned)f2bf(lo) | ((unsigned)f2bf(hi) << 16);
}
__device__ inline float bflo(unsigned u) { return __uint_as_float(u << 16); }
__device__ inline float bfhi(unsigned u) { return __uint_as_float(u & 0xffff0000u); }

// ---------------------------------------------------------------------------
// CSR build: degree -> 3-phase device-wide exclusive scan -> bucket fill
// ---------------------------------------------------------------------------
__global__ __launch_bounds__(256)
void degree_kernel(const int* __restrict__ dst, int* __restrict__ deg, int E)
{
    int e = blockIdx.x * 256 + threadIdx.x;
    if (e < E) atomicAdd(&deg[dst[e]], 1);
}

// Phase A: 1024 elems/block; exclusive-scan within block into row_ptr (local),
// per-block total into blk_sum.
__global__ __launch_bounds__(256)
void scan_local_kernel(const int* __restrict__ deg, int* __restrict__ local,
                       int* __restrict__ blk_sum, int N)
{
    __shared__ int tmp[256];
    const int tid = threadIdx.x;
    const int base = blockIdx.x * 1024 + tid * 4;
    int v0 = (base + 0 < N) ? deg[base + 0] : 0;
    int v1 = (base + 1 < N) ? deg[base + 1] : 0;
    int v2 = (base + 2 < N) ? deg[base + 2] : 0;
    int v3 = (base + 3 < N) ? deg[base + 3] : 0;
    const int s = v0 + v1 + v2 + v3;
    tmp[tid] = s;
    __syncthreads();
    for (int off = 1; off < 256; off <<= 1) {
        int t = (tid >= off) ? tmp[tid - off] : 0;
        __syncthreads();
        tmp[tid] += t;
        __syncthreads();
    }
    int run = tmp[tid] - s;                    // exclusive prefix of this thread
    if (base + 0 < N) local[base + 0] = run;  run += v0;
    if (base + 1 < N) local[base + 1] = run;  run += v1;
    if (base + 2 < N) local[base + 2] = run;  run += v2;
    if (base + 3 < N) local[base + 3] = run;
    if (tid == 255) blk_sum[blockIdx.x] = tmp[255];
}

// Phase B: single block scans block totals (B <= 256), writes exclusive block
// prefixes and the grand total into row_ptr[N].
__global__ __launch_bounds__(256)
void scan_block_kernel(const int* __restrict__ blk_sum, int* __restrict__ blk_pref,
                       int* __restrict__ total_out, int B)
{
    __shared__ int tmp[256];
    const int tid = threadIdx.x;
    int v = (tid < B) ? blk_sum[tid] : 0;
    tmp[tid] = v;
    __syncthreads();
    for (int off = 1; off < 256; off <<= 1) {
        int t = (tid >= off) ? tmp[tid - off] : 0;
        __syncthreads();
        tmp[tid] += t;
        __syncthreads();
    }
    if (tid < B) blk_pref[tid] = tmp[tid] - v;
    if (tid == 255) *total_out = tmp[255];
}

// Phase C: add block prefix, finalize row_ptr and offs.
__global__ __launch_bounds__(256)
void scan_add_kernel(int* __restrict__ row_ptr, int* __restrict__ offs,
                     const int* __restrict__ blk_pref, int N)
{
    const int base = blockIdx.x * 1024 + threadIdx.x * 4;
    const int p = blk_pref[blockIdx.x];
#pragma unroll
    for (int i = 0; i < 4; ++i) {
        int idx = base + i;
        if (idx < N) {
            int val = row_ptr[idx] + p;
            row_ptr[idx] = val;
            offs[idx] = val;
        }
    }
}

__global__ __launch_bounds__(256)
void csr_fill_kernel(const int* __restrict__ src, const int* __restrict__ dst,
                     int* __restrict__ offs, int* __restrict__ csr_src, int E)
{
    int e = blockIdx.x * 256 + threadIdx.x;
    if (e < E) {
        int p = atomicAdd(&offs[dst[e]], 1);
        csr_src[p] = src[e];
    }
}

// ---------------------------------------------------------------------------
// x fp32 -> bf16 into Acat1 cols 128..255 (uints 64..127 of the 128-uint row)
// ---------------------------------------------------------------------------
__global__ __launch_bounds__(256)
void prep_x_kernel(const float* __restrict__ x, unsigned* __restrict__ acat1, int N)
{
    int t = blockIdx.x * 256 + threadIdx.x;       // one per 2 floats, N*64 total
    if (t >= N * 64) return;
    int row = t >> 6, c = t & 63;
    float2 v = ((const float2*)x)[t];
    acat1[(size_t)row * 128 + 64 + c] = pack2(v.x, v.y);
}

// ---------------------------------------------------------------------------
// Pack fp32 weights (row-major K x 256, concat of up to 3 sources) into MFMA
// B-fragment layout: frag (kt,nt) is 64 lanes x 8 bf16;
//   lane l holds col j = nt*16+(l&15), k = kt*32+(l>>4)*8+e.
// ---------------------------------------------------------------------------
__global__ __launch_bounds__(256)
void pack_w_kernel(const float* __restrict__ WA, int ka,
                   const float* __restrict__ WB, int kb,
                   const float* __restrict__ WC,
                   unsigned short* __restrict__ out, int K)
{
    int t = blockIdx.x * 256 + threadIdx.x;       // t = ((kt*16)+nt)*64 + lane
    int total = (K / 32) * 16 * 64;
    if (t >= total) return;
    int lane = t & 63;
    int nt = (t >> 6) & 15;
    int kt = t >> 10;
    int j = nt * 16 + (lane & 15);
    unsigned short* o = out + (size_t)t * 8;
#pragma unroll
    for (int e = 0; e < 8; ++e) {
        int k = kt * 32 + ((lane >> 4) & 3) * 8 + e;
        float v;
        if (k < ka)      v = WA[(size_t)k * 256 + j];
        else if (k < kb) v = WB[(size_t)(k - ka) * 256 + j];
        else             v = WC[(size_t)(k - kb) * 256 + j];
        o[e] = f2bf(v);
    }
}

// ---------------------------------------------------------------------------
// Gather-mean of x_bf (Acat1 cols 128..255) -> Acat1 cols 0..127. Wave/node.
// 2-way edge unroll: two independent row loads in flight.
// ---------------------------------------------------------------------------
__global__ __launch_bounds__(256)
void gather1_kernel(const int* __restrict__ row_ptr, const int* __restrict__ csr_src,
                    unsigned* __restrict__ acat1, int N)
{
    int node = blockIdx.x * 4 + (threadIdx.x >> 6);
    int lane = threadIdx.x & 63;
    if (node >= N) return;
    int beg = row_ptr[node], end = row_ptr[node + 1];
    float a0 = 0.f, a1 = 0.f;
    float b0 = 0.f, b1 = 0.f;
    int e = beg;
    for (; e + 1 < end; e += 2) {
        int s0 = csr_src[e], s1 = csr_src[e + 1];
        unsigned u0 = acat1[(size_t)s0 * 128 + 64 + lane];
        unsigned u1 = acat1[(size_t)s1 * 128 + 64 + lane];
        a0 += bflo(u0); a1 += bfhi(u0);
        b0 += bflo(u1); b1 += bfhi(u1);
    }
    if (e < end) {
        unsigned u = acat1[(size_t)csr_src[e] * 128 + 64 + lane];
        a0 += bflo(u); a1 += bfhi(u);
    }
    a0 += b0; a1 += b1;
    float inv = 1.0f / fmaxf((float)(end - beg), 1.0f);
    acat1[(size_t)node * 128 + lane] = pack2(a0 * inv, a1 * inv);
}

// ---------------------------------------------------------------------------
// Gather-mean of h1_bf (Acat2 cols 256..511) -> Acat2 cols 0..255. Wave/node.
// uint2 loads (512B/row in one transaction) + 2-way edge unroll.
// ---------------------------------------------------------------------------
__global__ __launch_bounds__(256)
void gather2_kernel(const int* __restrict__ row_ptr, const int* __restrict__ csr_src,
                    unsigned* __restrict__ acat2, int N)
{
    int node = blockIdx.x * 4 + (threadIdx.x >> 6);
    int lane = threadIdx.x & 63;
    if (node >= N) return;
    int beg = row_ptr[node], end = row_ptr[node + 1];
    float a0 = 0.f, a1 = 0.f, a2 = 0.f, a3 = 0.f;
    float c0 = 0.f, c1 = 0.f, c2 = 0.f, c3 = 0.f;
    int e = beg;
    for (; e + 1 < end; e += 2) {
        int s0 = csr_src[e], s1 = csr_src[e + 1];
        const uint2 u = *(const uint2*)(acat2 + (size_t)s0 * 256 + 128 + lane * 2);
        const uint2 v = *(const uint2*)(acat2 + (size_t)s1 * 256 + 128 + lane * 2);
        a0 += bflo(u.x); a1 += bfhi(u.x); a2 += bflo(u.y); a3 += bfhi(u.y);
        c0 += bflo(v.x); c1 += bfhi(v.x); c2 += bflo(v.y); c3 += bfhi(v.y);
    }
    if (e < end) {
        const uint2 u = *(const uint2*)(acat2 + (size_t)csr_src[e] * 256 + 128 + lane * 2);
        a0 += bflo(u.x); a1 += bfhi(u.x); a2 += bflo(u.y); a3 += bfhi(u.y);
    }
    a0 += c0; a1 += c1; a2 += c2; a3 += c3;
    float inv = 1.0f / fmaxf((float)(end - beg), 1.0f);
    uint2 o;
    o.x = pack2(a0 * inv, a1 * inv);
    o.y = pack2(a2 * inv, a3 * inv);
    *(uint2*)(acat2 + (size_t)node * 256 + lane * 2) = o;
}

// ---------------------------------------------------------------------------
// GEMM1: h1 = relu(LN(Acat1[N,256] @ W1[256,256] + bl)) -> bf16 into Acat2 cols 256..511
// Block = 4 waves over 16 rows; wave owns cols wave*64..+63 (4 nt tiles).
// LN partial sums cross waves via tiny LDS.
// ---------------------------------------------------------------------------
__global__ __launch_bounds__(256, 4)
void gemm1_kernel(const short8v* __restrict__ A,     // Acat1: 32 frags per row
                  const short8v* __restrict__ Bpk,   // Wpk1: (kt*16+nt)*64+lane
                  const float* __restrict__ bl, const float* __restrict__ g,
                  const float* __restrict__ be,
                  unsigned short* __restrict__ h1out, // Acat2 ushort view, stride 512
                  int N)
{
    __shared__ float sS[4][16], sSS[4][16];
    const int lane = threadIdx.x & 63;
    const int wave = threadIdx.x >> 6;
    const int rbase = blockIdx.x * 16;
    int arow = rbase + (lane & 15);
    if (arow >= N) arow = N - 1;
    const short8v* Ar = A + (size_t)arow * 32 + (lane >> 4);

    f32x4 acc[4];
#pragma unroll
    for (int nt = 0; nt < 4; ++nt) acc[nt] = (f32x4){0.f, 0.f, 0.f, 0.f};

#pragma unroll
    for (int kt = 0; kt < 8; ++kt) {
        short8v a = Ar[kt * 4];
        const short8v* Bp = Bpk + (size_t)(kt * 16 + wave * 4) * 64 + lane;
#pragma unroll
        for (int nt = 0; nt < 4; ++nt)
            acc[nt] = __builtin_amdgcn_mfma_f32_16x16x32_bf16(a, Bp[(size_t)nt * 64], acc[nt], 0, 0, 0);
    }

    const int col0 = lane & 15;
    const int grp  = lane >> 4;                 // rows grp*4 + r
    float s[4] = {0,0,0,0}, ss[4] = {0,0,0,0};
#pragma unroll
    for (int nt = 0; nt < 4; ++nt) {
        float blv = bl[(wave * 4 + nt) * 16 + col0];
#pragma unroll
        for (int r = 0; r < 4; ++r) {
            float v = acc[nt][r] + blv;
            acc[nt][r] = v;
            s[r] += v; ss[r] += v * v;
        }
    }
#pragma unroll
    for (int off = 1; off < 16; off <<= 1) {
#pragma unroll
        for (int r = 0; r < 4; ++r) {
            s[r]  += __shfl_xor(s[r],  off);
            ss[r] += __shfl_xor(ss[r], off);
        }
    }
    if (col0 == 0) {
#pragma unroll
        for (int r = 0; r < 4; ++r) {
            sS[wave][grp * 4 + r]  = s[r];
            sSS[wave][grp * 4 + r] = ss[r];
        }
    }
    __syncthreads();
    float mu[4], inv[4];
#pragma unroll
    for (int r = 0; r < 4; ++r) {
        int row = grp * 4 + r;
        float S  = sS[0][row] + sS[1][row] + sS[2][row] + sS[3][row];
        float SS = sSS[0][row] + sSS[1][row] + sSS[2][row] + sSS[3][row];
        mu[r] = S * (1.f / 256.f);
        float var = SS * (1.f / 256.f) - mu[r] * mu[r];
        inv[r] = rsqrtf(var + LN_EPS);
    }
#pragma unroll
    for (int nt = 0; nt < 4; ++nt) {
        int col = (wave * 4 + nt) * 16 + col0;
        float gv = g[col], bv = be[col];
#pragma unroll
        for (int r = 0; r < 4; ++r) {
            int srow = rbase + grp * 4 + r;
            if (srow < N) {
                float v = (acc[nt][r] - mu[r]) * inv[r] * gv + bv;
                h1out[(size_t)srow * 512 + 256 + col] = f2bf(fmaxf(v, 0.f));
            }
        }
    }
}

// ---------------------------------------------------------------------------
// GEMM2: out = relu(LN(Acat2[N,512] @ W2[0:512] + bl2)) + (x_bf @ Wres + bres)
// Same 4-wave col-split; x_bf from Acat1 cols 128..255; Wres = Wpk2 kt 16..19.
// ---------------------------------------------------------------------------
__global__ __launch_bounds__(256, 4)
void gemm2_kernel(const short8v* __restrict__ A2,    // Acat2: 64 frags per row
                  const short8v* __restrict__ A1,    // Acat1: 32 frags per row
                  const short8v* __restrict__ Bpk,   // Wpk2: 20 kt
                  const float* __restrict__ bl, const float* __restrict__ g,
                  const float* __restrict__ be, const float* __restrict__ bres,
                  float* __restrict__ out, int N)
{
    __shared__ float sS[4][16], sSS[4][16];
    const int lane = threadIdx.x & 63;
    const int wave = threadIdx.x >> 6;
    const int rbase = blockIdx.x * 16;
    int arow = rbase + (lane & 15);
    if (arow >= N) arow = N - 1;
    const short8v* Ar2 = A2 + (size_t)arow * 64 + (lane >> 4);
    const short8v* Ar1 = A1 + (size_t)arow * 32 + 16 + (lane >> 4);

    f32x4 accs[4], accb[4];
#pragma unroll
    for (int nt = 0; nt < 4; ++nt) {
        accs[nt] = (f32x4){0.f, 0.f, 0.f, 0.f};
        accb[nt] = (f32x4){0.f, 0.f, 0.f, 0.f};
    }

#pragma unroll
    for (int kt = 0; kt < 16; ++kt) {
        short8v a = Ar2[kt * 4];
        const short8v* Bp = Bpk + (size_t)(kt * 16 + wave * 4) * 64 + lane;
#pragma unroll
        for (int nt = 0; nt < 4; ++nt)
            accs[nt] = __builtin_amdgcn_mfma_f32_16x16x32_bf16(a, Bp[(size_t)nt * 64], accs[nt], 0, 0, 0);
    }
#pragma unroll
    for (int kt = 0; kt < 4; ++kt) {
        short8v a = Ar1[kt * 4];
        const short8v* Bp = Bpk + (size_t)((16 + kt) * 16 + wave * 4) * 64 + lane;
#pragma unroll
        for (int nt = 0; nt < 4; ++nt)
            accb[nt] = __builtin_amdgcn_mfma_f32_16x16x32_bf16(a, Bp[(size_t)nt * 64], accb[nt], 0, 0, 0);
    }

    const int col0 = lane & 15;
    const int grp  = lane >> 4;
    float s[4] = {0,0,0,0}, ss[4] = {0,0,0,0};
#pragma unroll
    for (int nt = 0; nt < 4; ++nt) {
        float blv = bl[(wave * 4 + nt) * 16 + col0];
#pragma unroll
        for (int r = 0; r < 4; ++r) {
            float v = accs[nt][r] + blv;
            accs[nt][r] = v;
            s[r] += v; ss[r] += v * v;
        }
    }
#pragma unroll
    for (int off = 1; off < 16; off <<= 1) {
#pragma unroll
        for (int r = 0; r < 4; ++r) {
            s[r]  += __shfl_xor(s[r],  off);
            ss[r] += __shfl_xor(ss[r], off);
        }
    }
    if (col0 == 0) {
#pragma unroll
        for (int r = 0; r < 4; ++r) {
            sS[wave][grp * 4 + r]  = s[r];
            sSS[wave][grp * 4 + r] = ss[r];
        }
    }
    __syncthreads();
    float mu[4], inv[4];
#pragma unroll
    for (int r = 0; r < 4; ++r) {
        int row = grp * 4 + r;
        float S  = sS[0][row] + sS[1][row] + sS[2][row] + sS[3][row];
        float SS = sSS[0][row] + sSS[1][row] + sSS[2][row] + sSS[3][row];
        mu[r] = S * (1.f / 256.f);
        float var = SS * (1.f / 256.f) - mu[r] * mu[r];
        inv[r] = rsqrtf(var + LN_EPS);
    }
#pragma unroll
    for (int nt = 0; nt < 4; ++nt) {
        int col = (wave * 4 + nt) * 16 + col0;
        float gv = g[col], bv = be[col], brv = bres[col];
#pragma unroll
        for (int r = 0; r < 4; ++r) {
            int srow = rbase + grp * 4 + r;
            if (srow < N) {
                float v = (accs[nt][r] - mu[r]) * inv[r] * gv + bv;
                out[(size_t)srow * 256 + col] = fmaxf(v, 0.f) + accb[nt][r] + brv;
            }
        }
    }
}

extern "C" void kernel_launch(void* const* d_in, const int* in_sizes, int n_in,
                              void* d_out, int out_size, void* d_ws, size_t ws_size,
                              hipStream_t stream)
{
    const float* x    = (const float*)d_in[0];
    const int*   ei   = (const int*)d_in[1];
    const float* Wl1  = (const float*)d_in[2];
    const float* bl1  = (const float*)d_in[3];
    const float* Wr1  = (const float*)d_in[4];
    const float* g1   = (const float*)d_in[5];
    const float* be1  = (const float*)d_in[6];
    const float* Wl2  = (const float*)d_in[7];
    const float* bl2  = (const float*)d_in[8];
    const float* Wr2  = (const float*)d_in[9];
    const float* g2   = (const float*)d_in[10];
    const float* be2  = (const float*)d_in[11];
    const float* Wres = (const float*)d_in[12];
    const float* bres = (const float*)d_in[13];

    const int N = in_sizes[0] / 128;
    const int E = in_sizes[1] / 2;
    const int* src = ei;
    const int* dst = ei + E;

    // ws layout: Acat1 N*256 bf16 | Acat2 N*512 bf16 | Wpk1 256*256 bf16
    //            | Wpk2 640*256 bf16 | deg N | row_ptr N+1 | offs N | csr_src E
    //            | blk_sum 256 | blk_pref 256
    unsigned short* acat1 = (unsigned short*)d_ws;
    unsigned short* acat2 = acat1 + (size_t)N * 256;
    unsigned short* wpk1  = acat2 + (size_t)N * 512;
    unsigned short* wpk2  = wpk1 + 256 * 256;
    int* deg      = (int*)(wpk2 + 640 * 256);
    int* row_ptr  = deg + N;
    int* offs     = row_ptr + (N + 1);
    int* csr_src  = offs + N;
    int* blk_sum  = csr_src + E;
    int* blk_pref = blk_sum + 256;

    hipMemsetAsync(deg, 0, (size_t)N * sizeof(int), stream);

    const int eb = (E + 255) / 256;
    const int sb = (N + 1023) / 1024;           // scan blocks (<=256)
    degree_kernel<<<eb, 256, 0, stream>>>(dst, deg, E);
    scan_local_kernel<<<sb, 256, 0, stream>>>(deg, row_ptr, blk_sum, N);
    scan_block_kernel<<<1, 256, 0, stream>>>(blk_sum, blk_pref, row_ptr + N, sb);
    scan_add_kernel<<<sb, 256, 0, stream>>>(row_ptr, offs, blk_pref, N);
    csr_fill_kernel<<<eb, 256, 0, stream>>>(src, dst, offs, csr_src, E);

    prep_x_kernel<<<(N * 64 + 255) / 256, 256, 0, stream>>>(x, (unsigned*)acat1, N);
    pack_w_kernel<<<(8 * 16 * 64 + 255) / 256, 256, 0, stream>>>(Wl1, 128, Wr1, 256, Wr1, wpk1, 256);
    pack_w_kernel<<<(20 * 16 * 64 + 255) / 256, 256, 0, stream>>>(Wl2, 256, Wr2, 512, Wres, wpk2, 640);

    gather1_kernel<<<(N + 3) / 4, 256, 0, stream>>>(row_ptr, csr_src, (unsigned*)acat1, N);

    const int gb = (N + 15) / 16;
    gemm1_kernel<<<gb, 256, 0, stream>>>((const short8v*)acat1, (const short8v*)wpk1,
                                         bl1, g1, be1, acat2, N);

    gather2_kernel<<<(N + 3) / 4, 256, 0, stream>>>(row_ptr, csr_src, (unsigned*)acat2, N);

    gemm2_kernel<<<gb, 256, 0, stream>>>((const short8v*)acat2, (const short8v*)acat1,
                                         (const short8v*)wpk2, bl2, g2, be2, bres,
                                         (float*)d_out, N);
}

// Round 6
// 316.997 us; speedup vs baseline: 14.6457x; 1.0261x over previous
//
#include <hip/hip_runtime.h>

typedef short short8v __attribute__((ext_vector_type(8)));   // 8 bf16 (4 VGPRs)
typedef float f32x4  __attribute__((ext_vector_type(4)));    // MFMA acc

constexpr float LN_EPS = 1e-5f;

__device__ inline unsigned short f2bf(float f) {
    unsigned u = __float_as_uint(f);
    u += 0x7fffu + ((u >> 16) & 1u);          // RTN-even
    return (unsigned short)(u >> 16);
}
__device__ inline unsigned pack2(float lo, float hi) {
    return (unsigned)f2bf(lo) | ((unsigned)f2bf(hi) << 16);
}
__device__ inline float bflo(unsigned u) { return __uint_as_float(u << 16); }
__device__ inline float bfhi(unsigned u) { return __uint_as_float(u & 0xffff0000u); }

// ---------------------------------------------------------------------------
// CSR build: degree -> 3-phase device-wide exclusive scan -> bucket fill
// ---------------------------------------------------------------------------
__global__ __launch_bounds__(256)
void degree_kernel(const int* __restrict__ dst, int* __restrict__ deg, int E)
{
    int e = blockIdx.x * 256 + threadIdx.x;
    if (e < E) atomicAdd(&deg[dst[e]], 1);
}

__global__ __launch_bounds__(256)
void scan_local_kernel(const int* __restrict__ deg, int* __restrict__ local,
                       int* __restrict__ blk_sum, int N)
{
    __shared__ int tmp[256];
    const int tid = threadIdx.x;
    const int base = blockIdx.x * 1024 + tid * 4;
    int v0 = (base + 0 < N) ? deg[base + 0] : 0;
    int v1 = (base + 1 < N) ? deg[base + 1] : 0;
    int v2 = (base + 2 < N) ? deg[base + 2] : 0;
    int v3 = (base + 3 < N) ? deg[base + 3] : 0;
    const int s = v0 + v1 + v2 + v3;
    tmp[tid] = s;
    __syncthreads();
    for (int off = 1; off < 256; off <<= 1) {
        int t = (tid >= off) ? tmp[tid - off] : 0;
        __syncthreads();
        tmp[tid] += t;
        __syncthreads();
    }
    int run = tmp[tid] - s;
    if (base + 0 < N) local[base + 0] = run;  run += v0;
    if (base + 1 < N) local[base + 1] = run;  run += v1;
    if (base + 2 < N) local[base + 2] = run;  run += v2;
    if (base + 3 < N) local[base + 3] = run;
    if (tid == 255) blk_sum[blockIdx.x] = tmp[255];
}

__global__ __launch_bounds__(256)
void scan_block_kernel(const int* __restrict__ blk_sum, int* __restrict__ blk_pref,
                       int* __restrict__ total_out, int B)
{
    __shared__ int tmp[256];
    const int tid = threadIdx.x;
    int v = (tid < B) ? blk_sum[tid] : 0;
    tmp[tid] = v;
    __syncthreads();
    for (int off = 1; off < 256; off <<= 1) {
        int t = (tid >= off) ? tmp[tid - off] : 0;
        __syncthreads();
        tmp[tid] += t;
        __syncthreads();
    }
    if (tid < B) blk_pref[tid] = tmp[tid] - v;
    if (tid == 255) *total_out = tmp[255];
}

__global__ __launch_bounds__(256)
void scan_add_kernel(int* __restrict__ row_ptr, int* __restrict__ offs,
                     const int* __restrict__ blk_pref, int N)
{
    const int base = blockIdx.x * 1024 + threadIdx.x * 4;
    const int p = blk_pref[blockIdx.x];
#pragma unroll
    for (int i = 0; i < 4; ++i) {
        int idx = base + i;
        if (idx < N) {
            int val = row_ptr[idx] + p;
            row_ptr[idx] = val;
            offs[idx] = val;
        }
    }
}

__global__ __launch_bounds__(256)
void csr_fill_kernel(const int* __restrict__ src, const int* __restrict__ dst,
                     int* __restrict__ offs, int* __restrict__ csr_src, int E)
{
    int e = blockIdx.x * 256 + threadIdx.x;
    if (e < E) {
        int p = atomicAdd(&offs[dst[e]], 1);
        csr_src[p] = src[e];
    }
}

// ---------------------------------------------------------------------------
// x fp32 -> bf16 into Acat1 cols 128..255
// ---------------------------------------------------------------------------
__global__ __launch_bounds__(256)
void prep_x_kernel(const float* __restrict__ x, unsigned* __restrict__ acat1, int N)
{
    int t = blockIdx.x * 256 + threadIdx.x;
    if (t >= N * 64) return;
    int row = t >> 6, c = t & 63;
    float2 v = ((const float2*)x)[t];
    acat1[(size_t)row * 128 + 64 + c] = pack2(v.x, v.y);
}

// ---------------------------------------------------------------------------
// Pack fp32 weights into MFMA B-fragment layout.
// ---------------------------------------------------------------------------
__global__ __launch_bounds__(256)
void pack_w_kernel(const float* __restrict__ WA, int ka,
                   const float* __restrict__ WB, int kb,
                   const float* __restrict__ WC,
                   unsigned short* __restrict__ out, int K)
{
    int t = blockIdx.x * 256 + threadIdx.x;
    int total = (K / 32) * 16 * 64;
    if (t >= total) return;
    int lane = t & 63;
    int nt = (t >> 6) & 15;
    int kt = t >> 10;
    int j = nt * 16 + (lane & 15);
    unsigned short* o = out + (size_t)t * 8;
#pragma unroll
    for (int e = 0; e < 8; ++e) {
        int k = kt * 32 + ((lane >> 4) & 3) * 8 + e;
        float v;
        if (k < ka)      v = WA[(size_t)k * 256 + j];
        else if (k < kb) v = WB[(size_t)(k - ka) * 256 + j];
        else             v = WC[(size_t)(k - kb) * 256 + j];
        o[e] = f2bf(v);
    }
}

// ---------------------------------------------------------------------------
// Gather-mean of x_bf -> Acat1 cols 0..127. Wave/node, 4-way edge unroll.
// ---------------------------------------------------------------------------
__global__ __launch_bounds__(256)
void gather1_kernel(const int* __restrict__ row_ptr, const int* __restrict__ csr_src,
                    unsigned* __restrict__ acat1, int N)
{
    int node = blockIdx.x * 4 + (threadIdx.x >> 6);
    int lane = threadIdx.x & 63;
    if (node >= N) return;
    int beg = row_ptr[node], end = row_ptr[node + 1];
    float a0 = 0.f, a1 = 0.f, b0 = 0.f, b1 = 0.f;
    float c0 = 0.f, c1 = 0.f, d0 = 0.f, d1 = 0.f;
    int e = beg;
    for (; e + 3 < end; e += 4) {
        int s0 = csr_src[e], s1 = csr_src[e + 1], s2 = csr_src[e + 2], s3 = csr_src[e + 3];
        unsigned u0 = acat1[(size_t)s0 * 128 + 64 + lane];
        unsigned u1 = acat1[(size_t)s1 * 128 + 64 + lane];
        unsigned u2 = acat1[(size_t)s2 * 128 + 64 + lane];
        unsigned u3 = acat1[(size_t)s3 * 128 + 64 + lane];
        a0 += bflo(u0); a1 += bfhi(u0);
        b0 += bflo(u1); b1 += bfhi(u1);
        c0 += bflo(u2); c1 += bfhi(u2);
        d0 += bflo(u3); d1 += bfhi(u3);
    }
    for (; e < end; ++e) {
        unsigned u = acat1[(size_t)csr_src[e] * 128 + 64 + lane];
        a0 += bflo(u); a1 += bfhi(u);
    }
    a0 += b0 + c0 + d0; a1 += b1 + c1 + d1;
    float inv = 1.0f / fmaxf((float)(end - beg), 1.0f);
    acat1[(size_t)node * 128 + lane] = pack2(a0 * inv, a1 * inv);
}

// ---------------------------------------------------------------------------
// Gather-mean of h1_bf -> Acat2 cols 0..255. Wave/node, uint2, 4-way unroll.
// ---------------------------------------------------------------------------
__global__ __launch_bounds__(256)
void gather2_kernel(const int* __restrict__ row_ptr, const int* __restrict__ csr_src,
                    unsigned* __restrict__ acat2, int N)
{
    int node = blockIdx.x * 4 + (threadIdx.x >> 6);
    int lane = threadIdx.x & 63;
    if (node >= N) return;
    int beg = row_ptr[node], end = row_ptr[node + 1];
    float a0 = 0.f, a1 = 0.f, a2 = 0.f, a3 = 0.f;
    float b0 = 0.f, b1 = 0.f, b2 = 0.f, b3 = 0.f;
    float c0 = 0.f, c1 = 0.f, c2 = 0.f, c3 = 0.f;
    float d0 = 0.f, d1 = 0.f, d2 = 0.f, d3 = 0.f;
    int e = beg;
    for (; e + 3 < end; e += 4) {
        int s0 = csr_src[e], s1 = csr_src[e + 1], s2 = csr_src[e + 2], s3 = csr_src[e + 3];
        const uint2 u = *(const uint2*)(acat2 + (size_t)s0 * 256 + 128 + lane * 2);
        const uint2 v = *(const uint2*)(acat2 + (size_t)s1 * 256 + 128 + lane * 2);
        const uint2 w = *(const uint2*)(acat2 + (size_t)s2 * 256 + 128 + lane * 2);
        const uint2 z = *(const uint2*)(acat2 + (size_t)s3 * 256 + 128 + lane * 2);
        a0 += bflo(u.x); a1 += bfhi(u.x); a2 += bflo(u.y); a3 += bfhi(u.y);
        b0 += bflo(v.x); b1 += bfhi(v.x); b2 += bflo(v.y); b3 += bfhi(v.y);
        c0 += bflo(w.x); c1 += bfhi(w.x); c2 += bflo(w.y); c3 += bfhi(w.y);
        d0 += bflo(z.x); d1 += bfhi(z.x); d2 += bflo(z.y); d3 += bfhi(z.y);
    }
    for (; e < end; ++e) {
        const uint2 u = *(const uint2*)(acat2 + (size_t)csr_src[e] * 256 + 128 + lane * 2);
        a0 += bflo(u.x); a1 += bfhi(u.x); a2 += bflo(u.y); a3 += bfhi(u.y);
    }
    a0 += b0 + c0 + d0; a1 += b1 + c1 + d1;
    a2 += b2 + c2 + d2; a3 += b3 + c3 + d3;
    float inv = 1.0f / fmaxf((float)(end - beg), 1.0f);
    uint2 o;
    o.x = pack2(a0 * inv, a1 * inv);
    o.y = pack2(a2 * inv, a3 * inv);
    *(uint2*)(acat2 + (size_t)node * 256 + lane * 2) = o;
}

// ---------------------------------------------------------------------------
// GEMM1: h1 = relu(LN(Acat1[N,256] @ W1 + bl)) -> bf16 into Acat2 cols 256..511
// Block = 4 waves over 32 rows; wave owns 64 cols, 2 MFMA row-groups.
// ---------------------------------------------------------------------------
__global__ __launch_bounds__(256, 4)
void gemm1_kernel(const short8v* __restrict__ A,     // Acat1: 32 frags per row
                  const short8v* __restrict__ Bpk,
                  const float* __restrict__ bl, const float* __restrict__ g,
                  const float* __restrict__ be,
                  unsigned short* __restrict__ h1out, // Acat2 ushort view, stride 512
                  int N)
{
    __shared__ float sS[4][32], sSS[4][32];
    const int lane = threadIdx.x & 63;
    const int wave = threadIdx.x >> 6;
    const int rbase = blockIdx.x * 32;
    int ar0 = rbase + (lane & 15);
    int ar1 = ar0 + 16;
    if (ar0 >= N) ar0 = N - 1;
    if (ar1 >= N) ar1 = N - 1;
    const short8v* Ar0 = A + (size_t)ar0 * 32 + (lane >> 4);
    const short8v* Ar1 = A + (size_t)ar1 * 32 + (lane >> 4);

    f32x4 acc[2][4];
#pragma unroll
    for (int rg = 0; rg < 2; ++rg)
#pragma unroll
        for (int nt = 0; nt < 4; ++nt) acc[rg][nt] = (f32x4){0.f, 0.f, 0.f, 0.f};

#pragma unroll
    for (int kt = 0; kt < 8; ++kt) {
        short8v a0 = Ar0[kt * 4];
        short8v a1 = Ar1[kt * 4];
        const short8v* Bp = Bpk + (size_t)(kt * 16 + wave * 4) * 64 + lane;
#pragma unroll
        for (int nt = 0; nt < 4; ++nt) {
            short8v b = Bp[(size_t)nt * 64];
            acc[0][nt] = __builtin_amdgcn_mfma_f32_16x16x32_bf16(a0, b, acc[0][nt], 0, 0, 0);
            acc[1][nt] = __builtin_amdgcn_mfma_f32_16x16x32_bf16(a1, b, acc[1][nt], 0, 0, 0);
        }
    }

    const int col0 = lane & 15;
    const int grp  = lane >> 4;
    float s[2][4] = {{0,0,0,0},{0,0,0,0}}, ss[2][4] = {{0,0,0,0},{0,0,0,0}};
#pragma unroll
    for (int nt = 0; nt < 4; ++nt) {
        float blv = bl[(wave * 4 + nt) * 16 + col0];
#pragma unroll
        for (int rg = 0; rg < 2; ++rg)
#pragma unroll
            for (int r = 0; r < 4; ++r) {
                float v = acc[rg][nt][r] + blv;
                acc[rg][nt][r] = v;
                s[rg][r] += v; ss[rg][r] += v * v;
            }
    }
#pragma unroll
    for (int off = 1; off < 16; off <<= 1) {
#pragma unroll
        for (int rg = 0; rg < 2; ++rg)
#pragma unroll
            for (int r = 0; r < 4; ++r) {
                s[rg][r]  += __shfl_xor(s[rg][r],  off);
                ss[rg][r] += __shfl_xor(ss[rg][r], off);
            }
    }
    if (col0 == 0) {
#pragma unroll
        for (int rg = 0; rg < 2; ++rg)
#pragma unroll
            for (int r = 0; r < 4; ++r) {
                sS[wave][rg * 16 + grp * 4 + r]  = s[rg][r];
                sSS[wave][rg * 16 + grp * 4 + r] = ss[rg][r];
            }
    }
    __syncthreads();
    float mu[2][4], inv[2][4];
#pragma unroll
    for (int rg = 0; rg < 2; ++rg)
#pragma unroll
        for (int r = 0; r < 4; ++r) {
            int row = rg * 16 + grp * 4 + r;
            float S  = sS[0][row] + sS[1][row] + sS[2][row] + sS[3][row];
            float SS = sSS[0][row] + sSS[1][row] + sSS[2][row] + sSS[3][row];
            mu[rg][r] = S * (1.f / 256.f);
            float var = SS * (1.f / 256.f) - mu[rg][r] * mu[rg][r];
            inv[rg][r] = rsqrtf(var + LN_EPS);
        }
#pragma unroll
    for (int nt = 0; nt < 4; ++nt) {
        int col = (wave * 4 + nt) * 16 + col0;
        float gv = g[col], bv = be[col];
#pragma unroll
        for (int rg = 0; rg < 2; ++rg)
#pragma unroll
            for (int r = 0; r < 4; ++r) {
                int srow = rbase + rg * 16 + grp * 4 + r;
                if (srow < N) {
                    float v = (acc[rg][nt][r] - mu[rg][r]) * inv[rg][r] * gv + bv;
                    h1out[(size_t)srow * 512 + 256 + col] = f2bf(fmaxf(v, 0.f));
                }
            }
    }
}

// ---------------------------------------------------------------------------
// GEMM2: out = relu(LN(Acat2[N,512] @ W2 + bl2)) + (x_bf @ Wres + bres)
// Block = 4 waves over 32 rows; wave owns 64 cols, 2 MFMA row-groups.
// ---------------------------------------------------------------------------
__global__ __launch_bounds__(256, 4)
void gemm2_kernel(const short8v* __restrict__ A2,    // Acat2: 64 frags per row
                  const short8v* __restrict__ A1,    // Acat1: 32 frags per row
                  const short8v* __restrict__ Bpk,   // Wpk2: 20 kt
                  const float* __restrict__ bl, const float* __restrict__ g,
                  const float* __restrict__ be, const float* __restrict__ bres,
                  float* __restrict__ out, int N)
{
    __shared__ float sS[4][32], sSS[4][32];
    const int lane = threadIdx.x & 63;
    const int wave = threadIdx.x >> 6;
    const int rbase = blockIdx.x * 32;
    int ar0 = rbase + (lane & 15);
    int ar1 = ar0 + 16;
    if (ar0 >= N) ar0 = N - 1;
    if (ar1 >= N) ar1 = N - 1;
    const short8v* Ar2_0 = A2 + (size_t)ar0 * 64 + (lane >> 4);
    const short8v* Ar2_1 = A2 + (size_t)ar1 * 64 + (lane >> 4);
    const short8v* Ar1_0 = A1 + (size_t)ar0 * 32 + 16 + (lane >> 4);
    const short8v* Ar1_1 = A1 + (size_t)ar1 * 32 + 16 + (lane >> 4);

    f32x4 accs[2][4], accb[2][4];
#pragma unroll
    for (int rg = 0; rg < 2; ++rg)
#pragma unroll
        for (int nt = 0; nt < 4; ++nt) {
            accs[rg][nt] = (f32x4){0.f, 0.f, 0.f, 0.f};
            accb[rg][nt] = (f32x4){0.f, 0.f, 0.f, 0.f};
        }

#pragma unroll
    for (int kt = 0; kt < 16; ++kt) {
        short8v a0 = Ar2_0[kt * 4];
        short8v a1 = Ar2_1[kt * 4];
        const short8v* Bp = Bpk + (size_t)(kt * 16 + wave * 4) * 64 + lane;
#pragma unroll
        for (int nt = 0; nt < 4; ++nt) {
            short8v b = Bp[(size_t)nt * 64];
            accs[0][nt] = __builtin_amdgcn_mfma_f32_16x16x32_bf16(a0, b, accs[0][nt], 0, 0, 0);
            accs[1][nt] = __builtin_amdgcn_mfma_f32_16x16x32_bf16(a1, b, accs[1][nt], 0, 0, 0);
        }
    }
#pragma unroll
    for (int kt = 0; kt < 4; ++kt) {
        short8v a0 = Ar1_0[kt * 4];
        short8v a1 = Ar1_1[kt * 4];
        const short8v* Bp = Bpk + (size_t)((16 + kt) * 16 + wave * 4) * 64 + lane;
#pragma unroll
        for (int nt = 0; nt < 4; ++nt) {
            short8v b = Bp[(size_t)nt * 64];
            accb[0][nt] = __builtin_amdgcn_mfma_f32_16x16x32_bf16(a0, b, accb[0][nt], 0, 0, 0);
            accb[1][nt] = __builtin_amdgcn_mfma_f32_16x16x32_bf16(a1, b, accb[1][nt], 0, 0, 0);
        }
    }

    const int col0 = lane & 15;
    const int grp  = lane >> 4;
    float s[2][4] = {{0,0,0,0},{0,0,0,0}}, ss[2][4] = {{0,0,0,0},{0,0,0,0}};
#pragma unroll
    for (int nt = 0; nt < 4; ++nt) {
        float blv = bl[(wave * 4 + nt) * 16 + col0];
#pragma unroll
        for (int rg = 0; rg < 2; ++rg)
#pragma unroll
            for (int r = 0; r < 4; ++r) {
                float v = accs[rg][nt][r] + blv;
                accs[rg][nt][r] = v;
                s[rg][r] += v; ss[rg][r] += v * v;
            }
    }
#pragma unroll
    for (int off = 1; off < 16; off <<= 1) {
#pragma unroll
        for (int rg = 0; rg < 2; ++rg)
#pragma unroll
            for (int r = 0; r < 4; ++r) {
                s[rg][r]  += __shfl_xor(s[rg][r],  off);
                ss[rg][r] += __shfl_xor(ss[rg][r], off);
            }
    }
    if (col0 == 0) {
#pragma unroll
        for (int rg = 0; rg < 2; ++rg)
#pragma unroll
            for (int r = 0; r < 4; ++r) {
                sS[wave][rg * 16 + grp * 4 + r]  = s[rg][r];
                sSS[wave][rg * 16 + grp * 4 + r] = ss[rg][r];
            }
    }
    __syncthreads();
    float mu[2][4], inv[2][4];
#pragma unroll
    for (int rg = 0; rg < 2; ++rg)
#pragma unroll
        for (int r = 0; r < 4; ++r) {
            int row = rg * 16 + grp * 4 + r;
            float S  = sS[0][row] + sS[1][row] + sS[2][row] + sS[3][row];
            float SS = sSS[0][row] + sSS[1][row] + sSS[2][row] + sSS[3][row];
            mu[rg][r] = S * (1.f / 256.f);
            float var = SS * (1.f / 256.f) - mu[rg][r] * mu[rg][r];
            inv[rg][r] = rsqrtf(var + LN_EPS);
        }
#pragma unroll
    for (int nt = 0; nt < 4; ++nt) {
        int col = (wave * 4 + nt) * 16 + col0;
        float gv = g[col], bv = be[col], brv = bres[col];
#pragma unroll
        for (int rg = 0; rg < 2; ++rg)
#pragma unroll
            for (int r = 0; r < 4; ++r) {
                int srow = rbase + rg * 16 + grp * 4 + r;
                if (srow < N) {
                    float v = (accs[rg][nt][r] - mu[rg][r]) * inv[rg][r] * gv + bv;
                    out[(size_t)srow * 256 + col] = fmaxf(v, 0.f) + accb[rg][nt][r] + brv;
                }
            }
    }
}

extern "C" void kernel_launch(void* const* d_in, const int* in_sizes, int n_in,
                              void* d_out, int out_size, void* d_ws, size_t ws_size,
                              hipStream_t stream)
{
    const float* x    = (const float*)d_in[0];
    const int*   ei   = (const int*)d_in[1];
    const float* Wl1  = (const float*)d_in[2];
    const float* bl1  = (const float*)d_in[3];
    const float* Wr1  = (const float*)d_in[4];
    const float* g1   = (const float*)d_in[5];
    const float* be1  = (const float*)d_in[6];
    const float* Wl2  = (const float*)d_in[7];
    const float* bl2  = (const float*)d_in[8];
    const float* Wr2  = (const float*)d_in[9];
    const float* g2   = (const float*)d_in[10];
    const float* be2  = (const float*)d_in[11];
    const float* Wres = (const float*)d_in[12];
    const float* bres = (const float*)d_in[13];

    const int N = in_sizes[0] / 128;
    const int E = in_sizes[1] / 2;
    const int* src = ei;
    const int* dst = ei + E;

    // ws layout: Acat1 N*256 bf16 | Acat2 N*512 bf16 | Wpk1 256*256 bf16
    //            | Wpk2 640*256 bf16 | deg N | row_ptr N+1 | offs N | csr_src E
    //            | blk_sum 256 | blk_pref 256
    unsigned short* acat1 = (unsigned short*)d_ws;
    unsigned short* acat2 = acat1 + (size_t)N * 256;
    unsigned short* wpk1  = acat2 + (size_t)N * 512;
    unsigned short* wpk2  = wpk1 + 256 * 256;
    int* deg      = (int*)(wpk2 + 640 * 256);
    int* row_ptr  = deg + N;
    int* offs     = row_ptr + (N + 1);
    int* csr_src  = offs + N;
    int* blk_sum  = csr_src + E;
    int* blk_pref = blk_sum + 256;

    hipMemsetAsync(deg, 0, (size_t)N * sizeof(int), stream);

    const int eb = (E + 255) / 256;
    const int sb = (N + 1023) / 1024;
    degree_kernel<<<eb, 256, 0, stream>>>(dst, deg, E);
    scan_local_kernel<<<sb, 256, 0, stream>>>(deg, row_ptr, blk_sum, N);
    scan_block_kernel<<<1, 256, 0, stream>>>(blk_sum, blk_pref, row_ptr + N, sb);
    scan_add_kernel<<<sb, 256, 0, stream>>>(row_ptr, offs, blk_pref, N);
    csr_fill_kernel<<<eb, 256, 0, stream>>>(src, dst, offs, csr_src, E);

    prep_x_kernel<<<(N * 64 + 255) / 256, 256, 0, stream>>>(x, (unsigned*)acat1, N);
    pack_w_kernel<<<(8 * 16 * 64 + 255) / 256, 256, 0, stream>>>(Wl1, 128, Wr1, 256, Wr1, wpk1, 256);
    pack_w_kernel<<<(20 * 16 * 64 + 255) / 256, 256, 0, stream>>>(Wl2, 256, Wr2, 512, Wres, wpk2, 640);

    gather1_kernel<<<(N + 3) / 4, 256, 0, stream>>>(row_ptr, csr_src, (unsigned*)acat1, N);

    const int gb = (N + 31) / 32;
    gemm1_kernel<<<gb, 256, 0, stream>>>((const short8v*)acat1, (const short8v*)wpk1,
                                         bl1, g1, be1, acat2, N);

    gather2_kernel<<<(N + 3) / 4, 256, 0, stream>>>(row_ptr, csr_src, (unsigned*)acat2, N);

    gemm2_kernel<<<gb, 256, 0, stream>>>((const short8v*)acat2, (const short8v*)acat1,
                                         (const short8v*)wpk2, bl2, g2, be2, bres,
                                         (float*)d_out, N);
}

// Round 7
// 287.983 us; speedup vs baseline: 16.1212x; 1.1007x over previous
//
#include <hip/hip_runtime.h>

typedef short short8v __attribute__((ext_vector_type(8)));   // 8 bf16 (4 VGPRs)
typedef float f32x4  __attribute__((ext_vector_type(4)));    // MFMA acc

constexpr float LN_EPS = 1e-5f;

__device__ inline unsigned short f2bf(float f) {
    unsigned u = __float_as_uint(f);
    u += 0x7fffu + ((u >> 16) & 1u);          // RTN-even
    return (unsigned short)(u >> 16);
}
__device__ inline unsigned pack2(float lo, float hi) {
    return (unsigned)f2bf(lo) | ((unsigned)f2bf(hi) << 16);
}
__device__ inline float bflo(unsigned u) { return __uint_as_float(u << 16); }
__device__ inline float bfhi(unsigned u) { return __uint_as_float(u & 0xffff0000u); }

// async global->LDS, 16B per lane (dest = wave-uniform base + lane*16)
__device__ inline void stage16(const void* gsrc, void* ldst) {
    __builtin_amdgcn_global_load_lds(
        (const __attribute__((address_space(1))) unsigned int*)gsrc,
        (__attribute__((address_space(3))) unsigned int*)ldst,
        16, 0, 0);
}

// ---------------------------------------------------------------------------
// CSR build: degree -> 3-phase device-wide exclusive scan -> bucket fill
// ---------------------------------------------------------------------------
__global__ __launch_bounds__(256)
void degree_kernel(const int* __restrict__ dst, int* __restrict__ deg, int E)
{
    int e = blockIdx.x * 256 + threadIdx.x;
    if (e < E) atomicAdd(&deg[dst[e]], 1);
}

__global__ __launch_bounds__(256)
void scan_local_kernel(const int* __restrict__ deg, int* __restrict__ local,
                       int* __restrict__ blk_sum, int N)
{
    __shared__ int tmp[256];
    const int tid = threadIdx.x;
    const int base = blockIdx.x * 1024 + tid * 4;
    int v0 = (base + 0 < N) ? deg[base + 0] : 0;
    int v1 = (base + 1 < N) ? deg[base + 1] : 0;
    int v2 = (base + 2 < N) ? deg[base + 2] : 0;
    int v3 = (base + 3 < N) ? deg[base + 3] : 0;
    const int s = v0 + v1 + v2 + v3;
    tmp[tid] = s;
    __syncthreads();
    for (int off = 1; off < 256; off <<= 1) {
        int t = (tid >= off) ? tmp[tid - off] : 0;
        __syncthreads();
        tmp[tid] += t;
        __syncthreads();
    }
    int run = tmp[tid] - s;
    if (base + 0 < N) local[base + 0] = run;  run += v0;
    if (base + 1 < N) local[base + 1] = run;  run += v1;
    if (base + 2 < N) local[base + 2] = run;  run += v2;
    if (base + 3 < N) local[base + 3] = run;
    if (tid == 255) blk_sum[blockIdx.x] = tmp[255];
}

__global__ __launch_bounds__(256)
void scan_block_kernel(const int* __restrict__ blk_sum, int* __restrict__ blk_pref,
                       int* __restrict__ total_out, int B)
{
    __shared__ int tmp[256];
    const int tid = threadIdx.x;
    int v = (tid < B) ? blk_sum[tid] : 0;
    tmp[tid] = v;
    __syncthreads();
    for (int off = 1; off < 256; off <<= 1) {
        int t = (tid >= off) ? tmp[tid - off] : 0;
        __syncthreads();
        tmp[tid] += t;
        __syncthreads();
    }
    if (tid < B) blk_pref[tid] = tmp[tid] - v;
    if (tid == 255) *total_out = tmp[255];
}

__global__ __launch_bounds__(256)
void scan_add_kernel(int* __restrict__ row_ptr, int* __restrict__ offs,
                     const int* __restrict__ blk_pref, int N)
{
    const int base = blockIdx.x * 1024 + threadIdx.x * 4;
    const int p = blk_pref[blockIdx.x];
#pragma unroll
    for (int i = 0; i < 4; ++i) {
        int idx = base + i;
        if (idx < N) {
            int val = row_ptr[idx] + p;
            row_ptr[idx] = val;
            offs[idx] = val;
        }
    }
}

__global__ __launch_bounds__(256)
void csr_fill_kernel(const int* __restrict__ src, const int* __restrict__ dst,
                     int* __restrict__ offs, int* __restrict__ csr_src, int E)
{
    int e = blockIdx.x * 256 + threadIdx.x;
    if (e < E) {
        int p = atomicAdd(&offs[dst[e]], 1);
        csr_src[p] = src[e];
    }
}

// ---------------------------------------------------------------------------
// x fp32 -> bf16 into Acat1 cols 128..255
// ---------------------------------------------------------------------------
__global__ __launch_bounds__(256)
void prep_x_kernel(const float* __restrict__ x, unsigned* __restrict__ acat1, int N)
{
    int t = blockIdx.x * 256 + threadIdx.x;
    if (t >= N * 64) return;
    int row = t >> 6, c = t & 63;
    float2 v = ((const float2*)x)[t];
    acat1[(size_t)row * 128 + 64 + c] = pack2(v.x, v.y);
}

// ---------------------------------------------------------------------------
// Pack fp32 weights into MFMA B-fragment layout.
// frag (kt,nt): lane l holds col j = nt*16+(l&15), k = kt*32+(l>>4)*8+e.
// ---------------------------------------------------------------------------
__global__ __launch_bounds__(256)
void pack_w_kernel(const float* __restrict__ WA, int ka,
                   const float* __restrict__ WB, int kb,
                   const float* __restrict__ WC,
                   unsigned short* __restrict__ out, int K)
{
    int t = blockIdx.x * 256 + threadIdx.x;
    int total = (K / 32) * 16 * 64;
    if (t >= total) return;
    int lane = t & 63;
    int nt = (t >> 6) & 15;
    int kt = t >> 10;
    int j = nt * 16 + (lane & 15);
    unsigned short* o = out + (size_t)t * 8;
#pragma unroll
    for (int e = 0; e < 8; ++e) {
        int k = kt * 32 + ((lane >> 4) & 3) * 8 + e;
        float v;
        if (k < ka)      v = WA[(size_t)k * 256 + j];
        else if (k < kb) v = WB[(size_t)(k - ka) * 256 + j];
        else             v = WC[(size_t)(k - kb) * 256 + j];
        o[e] = f2bf(v);
    }
}

// ---------------------------------------------------------------------------
// Gather-mean of x_bf -> Acat1 cols 0..127. Wave/node, 4-way edge unroll.
// ---------------------------------------------------------------------------
__global__ __launch_bounds__(256)
void gather1_kernel(const int* __restrict__ row_ptr, const int* __restrict__ csr_src,
                    unsigned* __restrict__ acat1, int N)
{
    int node = blockIdx.x * 4 + (threadIdx.x >> 6);
    int lane = threadIdx.x & 63;
    if (node >= N) return;
    int beg = row_ptr[node], end = row_ptr[node + 1];
    float a0 = 0.f, a1 = 0.f, b0 = 0.f, b1 = 0.f;
    float c0 = 0.f, c1 = 0.f, d0 = 0.f, d1 = 0.f;
    int e = beg;
    for (; e + 3 < end; e += 4) {
        int s0 = csr_src[e], s1 = csr_src[e + 1], s2 = csr_src[e + 2], s3 = csr_src[e + 3];
        unsigned u0 = acat1[(size_t)s0 * 128 + 64 + lane];
        unsigned u1 = acat1[(size_t)s1 * 128 + 64 + lane];
        unsigned u2 = acat1[(size_t)s2 * 128 + 64 + lane];
        unsigned u3 = acat1[(size_t)s3 * 128 + 64 + lane];
        a0 += bflo(u0); a1 += bfhi(u0);
        b0 += bflo(u1); b1 += bfhi(u1);
        c0 += bflo(u2); c1 += bfhi(u2);
        d0 += bflo(u3); d1 += bfhi(u3);
    }
    for (; e < end; ++e) {
        unsigned u = acat1[(size_t)csr_src[e] * 128 + 64 + lane];
        a0 += bflo(u); a1 += bfhi(u);
    }
    a0 += b0 + c0 + d0; a1 += b1 + c1 + d1;
    float inv = 1.0f / fmaxf((float)(end - beg), 1.0f);
    acat1[(size_t)node * 128 + lane] = pack2(a0 * inv, a1 * inv);
}

// ---------------------------------------------------------------------------
// Gather-mean of h1_bf -> Acat2 cols 0..255. Wave/node, uint2, 4-way unroll.
// ---------------------------------------------------------------------------
__global__ __launch_bounds__(256)
void gather2_kernel(const int* __restrict__ row_ptr, const int* __restrict__ csr_src,
                    unsigned* __restrict__ acat2, int N)
{
    int node = blockIdx.x * 4 + (threadIdx.x >> 6);
    int lane = threadIdx.x & 63;
    if (node >= N) return;
    int beg = row_ptr[node], end = row_ptr[node + 1];
    float a0 = 0.f, a1 = 0.f, a2 = 0.f, a3 = 0.f;
    float b0 = 0.f, b1 = 0.f, b2 = 0.f, b3 = 0.f;
    float c0 = 0.f, c1 = 0.f, c2 = 0.f, c3 = 0.f;
    float d0 = 0.f, d1 = 0.f, d2 = 0.f, d3 = 0.f;
    int e = beg;
    for (; e + 3 < end; e += 4) {
        int s0 = csr_src[e], s1 = csr_src[e + 1], s2 = csr_src[e + 2], s3 = csr_src[e + 3];
        const uint2 u = *(const uint2*)(acat2 + (size_t)s0 * 256 + 128 + lane * 2);
        const uint2 v = *(const uint2*)(acat2 + (size_t)s1 * 256 + 128 + lane * 2);
        const uint2 w = *(const uint2*)(acat2 + (size_t)s2 * 256 + 128 + lane * 2);
        const uint2 z = *(const uint2*)(acat2 + (size_t)s3 * 256 + 128 + lane * 2);
        a0 += bflo(u.x); a1 += bfhi(u.x); a2 += bflo(u.y); a3 += bfhi(u.y);
        b0 += bflo(v.x); b1 += bfhi(v.x); b2 += bflo(v.y); b3 += bfhi(v.y);
        c0 += bflo(w.x); c1 += bfhi(w.x); c2 += bflo(w.y); c3 += bfhi(w.y);
        d0 += bflo(z.x); d1 += bfhi(z.x); d2 += bflo(z.y); d3 += bfhi(z.y);
    }
    for (; e < end; ++e) {
        const uint2 u = *(const uint2*)(acat2 + (size_t)csr_src[e] * 256 + 128 + lane * 2);
        a0 += bflo(u.x); a1 += bfhi(u.x); a2 += bflo(u.y); a3 += bfhi(u.y);
    }
    a0 += b0 + c0 + d0; a1 += b1 + c1 + d1;
    a2 += b2 + c2 + d2; a3 += b3 + c3 + d3;
    float inv = 1.0f / fmaxf((float)(end - beg), 1.0f);
    uint2 o;
    o.x = pack2(a0 * inv, a1 * inv);
    o.y = pack2(a2 * inv, a3 * inv);
    *(uint2*)(acat2 + (size_t)node * 256 + lane * 2) = o;
}

// ---------------------------------------------------------------------------
// GEMM1: h1 = relu(LN(Acat1[N,256] @ W1 + bl)) -> bf16 into Acat2 cols 256..511
// Block = 4 waves x 16 rows (64 rows); each wave owns ALL 256 cols (16 nt).
// B staged per-kt into LDS (16KB), double-buffered, global_load_lds prefetch.
// LN is wave-local (16-lane shfl groups).
// ---------------------------------------------------------------------------
__global__ __launch_bounds__(256, 3)
void gemm1_kernel(const short8v* __restrict__ A,     // Acat1: 32 frags per row
                  const unsigned short* __restrict__ Bpk,  // Wpk1: 8 kt * 16KB
                  const float* __restrict__ bl, const float* __restrict__ g,
                  const float* __restrict__ be,
                  unsigned short* __restrict__ h1out, // Acat2 ushort view, stride 512
                  int N)
{
    __shared__ short8v bbuf[2][16][64];               // 2 x 16KB
    const int tid  = threadIdx.x;
    const int lane = tid & 63;
    const int wave = tid >> 6;
    const int rbase = blockIdx.x * 64 + wave * 16;
    int arow = rbase + (lane & 15);
    if (arow >= N) arow = N - 1;
    const short8v* Ar = A + (size_t)arow * 32 + (lane >> 4);
    const char* bsrc = (const char*)Bpk;

    f32x4 acc[16];
#pragma unroll
    for (int nt = 0; nt < 16; ++nt) acc[nt] = (f32x4){0.f, 0.f, 0.f, 0.f};

    // prologue: stage kt=0
#pragma unroll
    for (int i = 0; i < 4; ++i)
        stage16(bsrc + i * 4096 + tid * 16, (char*)bbuf + i * 4096 + tid * 16);
    __syncthreads();

    short8v a = Ar[0];
    int cur = 0;
    for (int kt = 0; kt < 8; ++kt) {
        short8v an = (kt < 7) ? Ar[(kt + 1) * 4] : a;     // A one kt ahead
        if (kt + 1 < 8) {
            const char* s = bsrc + (size_t)(kt + 1) * 16384;
            char* d = (char*)bbuf + (size_t)(cur ^ 1) * 16384;
#pragma unroll
            for (int i = 0; i < 4; ++i)
                stage16(s + i * 4096 + tid * 16, d + i * 4096 + tid * 16);
        }
#pragma unroll
        for (int nt = 0; nt < 16; ++nt)
            acc[nt] = __builtin_amdgcn_mfma_f32_16x16x32_bf16(a, bbuf[cur][nt][lane], acc[nt], 0, 0, 0);
        __syncthreads();
        cur ^= 1;
        a = an;
    }

    // epilogue: bias, wave-local LN (16-lane groups), relu, bf16 store
    const int col0 = lane & 15;
    const int grp  = lane >> 4;
    float s[4] = {0,0,0,0}, ss[4] = {0,0,0,0};
#pragma unroll
    for (int nt = 0; nt < 16; ++nt) {
        float blv = bl[nt * 16 + col0];
#pragma unroll
        for (int r = 0; r < 4; ++r) {
            float v = acc[nt][r] + blv;
            acc[nt][r] = v;
            s[r] += v; ss[r] += v * v;
        }
    }
#pragma unroll
    for (int off = 1; off < 16; off <<= 1) {
#pragma unroll
        for (int r = 0; r < 4; ++r) {
            s[r]  += __shfl_xor(s[r],  off);
            ss[r] += __shfl_xor(ss[r], off);
        }
    }
    float mu[4], inv[4];
#pragma unroll
    for (int r = 0; r < 4; ++r) {
        mu[r] = s[r] * (1.f / 256.f);
        float var = ss[r] * (1.f / 256.f) - mu[r] * mu[r];
        inv[r] = rsqrtf(var + LN_EPS);
    }
#pragma unroll
    for (int nt = 0; nt < 16; ++nt) {
        int col = nt * 16 + col0;
        float gv = g[col], bv = be[col];
#pragma unroll
        for (int r = 0; r < 4; ++r) {
            int srow = rbase + grp * 4 + r;
            if (srow < N) {
                float v = (acc[nt][r] - mu[r]) * inv[r] * gv + bv;
                h1out[(size_t)srow * 512 + 256 + col] = f2bf(fmaxf(v, 0.f));
            }
        }
    }
}

// ---------------------------------------------------------------------------
// GEMM2: out = relu(LN(Acat2[N,512] @ W2 + bl2)) + (x_bf @ Wres + bres)
// Same structure, 20 kt total. After kt 0..15: in-place LN->relu transform of
// accs, then kt 16..19 (residual GEMM) ACCUMULATES into accs via MFMA C-in.
// ---------------------------------------------------------------------------
__global__ __launch_bounds__(256, 3)
void gemm2_kernel(const short8v* __restrict__ A2,    // Acat2: 64 frags per row
                  const short8v* __restrict__ A1,    // Acat1: 32 frags per row
                  const unsigned short* __restrict__ Bpk,  // Wpk2: 20 kt * 16KB
                  const float* __restrict__ bl, const float* __restrict__ g,
                  const float* __restrict__ be, const float* __restrict__ bres,
                  float* __restrict__ out, int N)
{
    __shared__ short8v bbuf[2][16][64];               // 2 x 16KB
    const int tid  = threadIdx.x;
    const int lane = tid & 63;
    const int wave = tid >> 6;
    const int rbase = blockIdx.x * 64 + wave * 16;
    int arow = rbase + (lane & 15);
    if (arow >= N) arow = N - 1;
    const short8v* Ar2 = A2 + (size_t)arow * 64 + (lane >> 4);
    const short8v* Ar1 = A1 + (size_t)arow * 32 + 16 + (lane >> 4);
    const char* bsrc = (const char*)Bpk;

    f32x4 accs[16];
#pragma unroll
    for (int nt = 0; nt < 16; ++nt) accs[nt] = (f32x4){0.f, 0.f, 0.f, 0.f};

    // prologue: stage kt=0
#pragma unroll
    for (int i = 0; i < 4; ++i)
        stage16(bsrc + i * 4096 + tid * 16, (char*)bbuf + i * 4096 + tid * 16);
    __syncthreads();

    short8v a = Ar2[0];
    int cur = 0;
    for (int kt = 0; kt < 16; ++kt) {
        short8v an = (kt < 15) ? Ar2[(kt + 1) * 4] : Ar1[0];
        {
            const char* s = bsrc + (size_t)(kt + 1) * 16384;
            char* d = (char*)bbuf + (size_t)(cur ^ 1) * 16384;
#pragma unroll
            for (int i = 0; i < 4; ++i)
                stage16(s + i * 4096 + tid * 16, d + i * 4096 + tid * 16);
        }
#pragma unroll
        for (int nt = 0; nt < 16; ++nt)
            accs[nt] = __builtin_amdgcn_mfma_f32_16x16x32_bf16(a, bbuf[cur][nt][lane], accs[nt], 0, 0, 0);
        __syncthreads();
        cur ^= 1;
        a = an;
    }

    // in-place: accs <- relu(LN(accs + bl))   (wave-local, register-only)
    const int col0 = lane & 15;
    const int grp  = lane >> 4;
    {
        float s[4] = {0,0,0,0}, ss[4] = {0,0,0,0};
#pragma unroll
        for (int nt = 0; nt < 16; ++nt) {
            float blv = bl[nt * 16 + col0];
#pragma unroll
            for (int r = 0; r < 4; ++r) {
                float v = accs[nt][r] + blv;
                accs[nt][r] = v;
                s[r] += v; ss[r] += v * v;
            }
        }
#pragma unroll
        for (int off = 1; off < 16; off <<= 1) {
#pragma unroll
            for (int r = 0; r < 4; ++r) {
                s[r]  += __shfl_xor(s[r],  off);
                ss[r] += __shfl_xor(ss[r], off);
            }
        }
        float mu[4], inv[4];
#pragma unroll
        for (int r = 0; r < 4; ++r) {
            mu[r] = s[r] * (1.f / 256.f);
            float var = ss[r] * (1.f / 256.f) - mu[r] * mu[r];
            inv[r] = rsqrtf(var + LN_EPS);
        }
#pragma unroll
        for (int nt = 0; nt < 16; ++nt) {
            int col = nt * 16 + col0;
            float gv = g[col], bv = be[col];
#pragma unroll
            for (int r = 0; r < 4; ++r) {
                float v = (accs[nt][r] - mu[r]) * inv[r] * gv + bv;
                accs[nt][r] = fmaxf(v, 0.f);
            }
        }
    }

    // residual GEMM kt 16..19 accumulates on top of relu(LN(.))
    for (int kt = 16; kt < 20; ++kt) {
        short8v an = (kt < 19) ? Ar1[(kt - 15) * 4] : a;
        if (kt + 1 < 20) {
            const char* s = bsrc + (size_t)(kt + 1) * 16384;
            char* d = (char*)bbuf + (size_t)(cur ^ 1) * 16384;
#pragma unroll
            for (int i = 0; i < 4; ++i)
                stage16(s + i * 4096 + tid * 16, d + i * 4096 + tid * 16);
        }
#pragma unroll
        for (int nt = 0; nt < 16; ++nt)
            accs[nt] = __builtin_amdgcn_mfma_f32_16x16x32_bf16(a, bbuf[cur][nt][lane], accs[nt], 0, 0, 0);
        __syncthreads();
        cur ^= 1;
        a = an;
    }

#pragma unroll
    for (int nt = 0; nt < 16; ++nt) {
        int col = nt * 16 + col0;
        float brv = bres[col];
#pragma unroll
        for (int r = 0; r < 4; ++r) {
            int srow = rbase + grp * 4 + r;
            if (srow < N)
                out[(size_t)srow * 256 + col] = accs[nt][r] + brv;
        }
    }
}

extern "C" void kernel_launch(void* const* d_in, const int* in_sizes, int n_in,
                              void* d_out, int out_size, void* d_ws, size_t ws_size,
                              hipStream_t stream)
{
    const float* x    = (const float*)d_in[0];
    const int*   ei   = (const int*)d_in[1];
    const float* Wl1  = (const float*)d_in[2];
    const float* bl1  = (const float*)d_in[3];
    const float* Wr1  = (const float*)d_in[4];
    const float* g1   = (const float*)d_in[5];
    const float* be1  = (const float*)d_in[6];
    const float* Wl2  = (const float*)d_in[7];
    const float* bl2  = (const float*)d_in[8];
    const float* Wr2  = (const float*)d_in[9];
    const float* g2   = (const float*)d_in[10];
    const float* be2  = (const float*)d_in[11];
    const float* Wres = (const float*)d_in[12];
    const float* bres = (const float*)d_in[13];

    const int N = in_sizes[0] / 128;
    const int E = in_sizes[1] / 2;
    const int* src = ei;
    const int* dst = ei + E;

    // ws layout: Acat1 N*256 bf16 | Acat2 N*512 bf16 | Wpk1 256*256 bf16
    //            | Wpk2 640*256 bf16 | deg N | row_ptr N+1 | offs N | csr_src E
    //            | blk_sum 256 | blk_pref 256
    unsigned short* acat1 = (unsigned short*)d_ws;
    unsigned short* acat2 = acat1 + (size_t)N * 256;
    unsigned short* wpk1  = acat2 + (size_t)N * 512;
    unsigned short* wpk2  = wpk1 + 256 * 256;
    int* deg      = (int*)(wpk2 + 640 * 256);
    int* row_ptr  = deg + N;
    int* offs     = row_ptr + (N + 1);
    int* csr_src  = offs + N;
    int* blk_sum  = csr_src + E;
    int* blk_pref = blk_sum + 256;

    hipMemsetAsync(deg, 0, (size_t)N * sizeof(int), stream);

    const int eb = (E + 255) / 256;
    const int sb = (N + 1023) / 1024;
    degree_kernel<<<eb, 256, 0, stream>>>(dst, deg, E);
    scan_local_kernel<<<sb, 256, 0, stream>>>(deg, row_ptr, blk_sum, N);
    scan_block_kernel<<<1, 256, 0, stream>>>(blk_sum, blk_pref, row_ptr + N, sb);
    scan_add_kernel<<<sb, 256, 0, stream>>>(row_ptr, offs, blk_pref, N);
    csr_fill_kernel<<<eb, 256, 0, stream>>>(src, dst, offs, csr_src, E);

    prep_x_kernel<<<(N * 64 + 255) / 256, 256, 0, stream>>>(x, (unsigned*)acat1, N);
    pack_w_kernel<<<(8 * 16 * 64 + 255) / 256, 256, 0, stream>>>(Wl1, 128, Wr1, 256, Wr1, wpk1, 256);
    pack_w_kernel<<<(20 * 16 * 64 + 255) / 256, 256, 0, stream>>>(Wl2, 256, Wr2, 512, Wres, wpk2, 640);

    gather1_kernel<<<(N + 3) / 4, 256, 0, stream>>>(row_ptr, csr_src, (unsigned*)acat1, N);

    const int gb = (N + 63) / 64;
    gemm1_kernel<<<gb, 256, 0, stream>>>((const short8v*)acat1, wpk1,
                                         bl1, g1, be1, acat2, N);

    gather2_kernel<<<(N + 3) / 4, 256, 0, stream>>>(row_ptr, csr_src, (unsigned*)acat2, N);

    gemm2_kernel<<<gb, 256, 0, stream>>>((const short8v*)acat2, (const short8v*)acat1,
                                         wpk2, bl2, g2, be2, bres,
                                         (float*)d_out, N);
}